// Round 1
// baseline (1052.987 us; speedup 1.0000x reference)
//
#include <hip/hip_runtime.h>

#define DIN 128
#define DHID 256

// ---------------- CSR build ----------------

__global__ void count_kernel(const int* __restrict__ dst, int* __restrict__ cnt, int E) {
    for (int e = blockIdx.x * blockDim.x + threadIdx.x; e < E; e += gridDim.x * blockDim.x)
        atomicAdd(&cnt[dst[e]], 1);
}

__global__ void scan_kernel(const int* __restrict__ cnt, int* __restrict__ rs, int n) {
    __shared__ int sums[1024];
    int tid = threadIdx.x;
    int per = n / 1024 + 1;
    int base = tid * per;
    int s = 0;
    for (int i = 0; i < per; i++) {
        int idx = base + i;
        if (idx < n) s += cnt[idx];
    }
    int mine = s;
    sums[tid] = s;
    __syncthreads();
    for (int off = 1; off < 1024; off <<= 1) {
        int v = (tid >= off) ? sums[tid - off] : 0;
        __syncthreads();
        sums[tid] += v;
        __syncthreads();
    }
    int run = sums[tid] - mine;  // exclusive prefix of my chunk
    for (int i = 0; i < per; i++) {
        int idx = base + i;
        if (idx < n) {
            rs[idx] = run;
            run += cnt[idx];
        } else if (idx == n) {
            rs[n] = run;
        }
    }
}

__global__ void fill_kernel(const int* __restrict__ src, const int* __restrict__ dst,
                            const int* __restrict__ rs, int* __restrict__ cur,
                            int* __restrict__ nbr, int E) {
    for (int e = blockIdx.x * blockDim.x + threadIdx.x; e < E; e += gridDim.x * blockDim.x) {
        int d = dst[e];
        int p = atomicAdd(&cur[d], 1);
        nbr[rs[d] + p] = src[e];
    }
}

// ---------------- segment mean (D=128) ----------------
// ADD=0: out = mean ; ADD=1: out += mean
template <int ADD>
__global__ void segmean_kernel(const float* __restrict__ feat, const int* __restrict__ rs,
                               const int* __restrict__ nbr, const int* __restrict__ cnt,
                               float* __restrict__ out) {
    int i = blockIdx.x;
    int f = threadIdx.x;  // 128 threads
    int b = rs[i], e2 = rs[i + 1];
    float acc = 0.f;
    int j = b;
    for (; j + 4 <= e2; j += 4) {
        int s0 = nbr[j], s1 = nbr[j + 1], s2 = nbr[j + 2], s3 = nbr[j + 3];
        float v0 = feat[s0 * DIN + f];
        float v1 = feat[s1 * DIN + f];
        float v2 = feat[s2 * DIN + f];
        float v3 = feat[s3 * DIN + f];
        acc += v0 + v1 + v2 + v3;
    }
    for (; j < e2; j++) acc += feat[nbr[j] * DIN + f];
    int dg = cnt[i];
    float inv = 1.0f / (float)(dg > 1 ? dg : 1);
    int o = i * DIN + f;
    if (ADD)
        out[o] += acc * inv;
    else
        out[o] = acc * inv;
}

// ---------------- GEMM 1: h = relu(x@Wr0 + agg@Wl0 + bl0), [N,128]x[128,256] twice ----------------
// block tile 64 rows x 256 cols, 256 threads, 8x8 per thread (cols strided by 32)

__launch_bounds__(256, 2)
__global__ void gemm1_kernel(const float* __restrict__ x, const float* __restrict__ agg,
                             const float* __restrict__ Wr0, const float* __restrict__ Wl0,
                             const float* __restrict__ bl0, float* __restrict__ h, int n) {
    __shared__ float As[64][36];    // [row][kk], padded
    __shared__ float Ws[32][260];   // [kk][col], padded
    int tx = threadIdx.x;
    int row0 = blockIdx.x * 64;
    int tr = tx >> 5, tc = tx & 31;
    float acc[8][8];
#pragma unroll
    for (int r = 0; r < 8; r++)
#pragma unroll
        for (int j = 0; j < 8; j++) acc[r][j] = 0.f;

    int arow = tx >> 2, aq = tx & 3;
    int grow = row0 + arow;
    if (grow > n - 1) grow = n - 1;
    int wk = tx >> 3, c0 = (tx & 7) * 32;

    for (int p = 0; p < 8; p++) {
        const float* A = (p < 4) ? x : agg;
        const float* W = (p < 4) ? Wr0 : Wl0;
        int koff = (p & 3) * 32;
        {  // stage A tile [64][32]
            const float* srcp = A + (size_t)grow * 128 + koff + aq * 8;
            float4 v0 = *(const float4*)(srcp);
            float4 v1 = *(const float4*)(srcp + 4);
            *(float4*)&As[arow][aq * 8] = v0;
            *(float4*)&As[arow][aq * 8 + 4] = v1;
        }
        {  // stage W tile [32][256]
            const float* wsrc = W + (size_t)(koff + wk) * 256 + c0;
#pragma unroll
            for (int m = 0; m < 8; m++)
                *(float4*)&Ws[wk][c0 + m * 4] = *(const float4*)(wsrc + m * 4);
        }
        __syncthreads();
#pragma unroll
        for (int kk = 0; kk < 32; kk++) {
            float a[8], wv[8];
#pragma unroll
            for (int r = 0; r < 8; r++) a[r] = As[tr * 8 + r][kk];
#pragma unroll
            for (int j = 0; j < 8; j++) wv[j] = Ws[kk][tc + 32 * j];
#pragma unroll
            for (int r = 0; r < 8; r++)
#pragma unroll
                for (int j = 0; j < 8; j++) acc[r][j] = fmaf(a[r], wv[j], acc[r][j]);
        }
        __syncthreads();
    }
#pragma unroll
    for (int r = 0; r < 8; r++) {
        int row = row0 + tr * 8 + r;
        if (row < n) {
#pragma unroll
            for (int j = 0; j < 8; j++) {
                int c = tc + 32 * j;
                float v = acc[r][j] + bl0[c];
                h[(size_t)row * 256 + c] = v > 0.f ? v : 0.f;
            }
        }
    }
}

// ---------------- GEMM 2: [N,256] x [256,256] where W = [Wl1 | Wr1] ----------------
// cols 0..127 -> z (pre-aggregation), cols 128..255 -> out (self term + bias)

__launch_bounds__(256, 2)
__global__ void gemm2_kernel(const float* __restrict__ h, const float* __restrict__ Wl1,
                             const float* __restrict__ Wr1, const float* __restrict__ bl1,
                             float* __restrict__ z, float* __restrict__ outp, int n) {
    __shared__ float As[64][36];
    __shared__ float Ws[32][260];
    int tx = threadIdx.x;
    int row0 = blockIdx.x * 64;
    int tr = tx >> 5, tc = tx & 31;
    float acc[8][8];
#pragma unroll
    for (int r = 0; r < 8; r++)
#pragma unroll
        for (int j = 0; j < 8; j++) acc[r][j] = 0.f;

    int arow = tx >> 2, aq = tx & 3;
    int grow = row0 + arow;
    if (grow > n - 1) grow = n - 1;
    int wk = tx >> 3, c0 = (tx & 7) * 32;

    for (int p = 0; p < 8; p++) {
        int koff = p * 32;
        {  // stage A tile from h (stride 256)
            const float* srcp = h + (size_t)grow * 256 + koff + aq * 8;
            float4 v0 = *(const float4*)(srcp);
            float4 v1 = *(const float4*)(srcp + 4);
            *(float4*)&As[arow][aq * 8] = v0;
            *(float4*)&As[arow][aq * 8 + 4] = v1;
        }
        {  // stage W tile: [Wl1 | Wr1]
            int kk2 = koff + wk;
            const float* wsrc = (c0 < 128) ? (Wl1 + (size_t)kk2 * 128 + c0)
                                           : (Wr1 + (size_t)kk2 * 128 + (c0 - 128));
#pragma unroll
            for (int m = 0; m < 8; m++)
                *(float4*)&Ws[wk][c0 + m * 4] = *(const float4*)(wsrc + m * 4);
        }
        __syncthreads();
#pragma unroll
        for (int kk = 0; kk < 32; kk++) {
            float a[8], wv[8];
#pragma unroll
            for (int r = 0; r < 8; r++) a[r] = As[tr * 8 + r][kk];
#pragma unroll
            for (int j = 0; j < 8; j++) wv[j] = Ws[kk][tc + 32 * j];
#pragma unroll
            for (int r = 0; r < 8; r++)
#pragma unroll
                for (int j = 0; j < 8; j++) acc[r][j] = fmaf(a[r], wv[j], acc[r][j]);
        }
        __syncthreads();
    }
#pragma unroll
    for (int r = 0; r < 8; r++) {
        int row = row0 + tr * 8 + r;
        if (row < n) {
#pragma unroll
            for (int j = 0; j < 4; j++) {
                int c = tc + 32 * j;
                z[(size_t)row * 128 + c] = acc[r][j];
            }
#pragma unroll
            for (int j = 4; j < 8; j++) {
                int c = tc + 32 * (j - 4);
                outp[(size_t)row * 128 + c] = acc[r][j] + bl1[c];
            }
        }
    }
}

// ---------------- launch ----------------

extern "C" void kernel_launch(void* const* d_in, const int* in_sizes, int n_in,
                              void* d_out, int out_size, void* d_ws, size_t ws_size,
                              hipStream_t stream) {
    const float* x = (const float*)d_in[0];
    const int* ei = (const int*)d_in[1];
    const float* Wl0 = (const float*)d_in[2];
    const float* bl0 = (const float*)d_in[3];
    const float* Wr0 = (const float*)d_in[4];
    const float* Wl1 = (const float*)d_in[5];
    const float* bl1 = (const float*)d_in[6];
    const float* Wr1 = (const float*)d_in[7];
    float* outp = (float*)d_out;

    int n = in_sizes[0] / DIN;   // 100000
    int E = in_sizes[1] / 2;     // 1600000
    const int* srcv = ei;
    const int* dstv = ei + E;

    char* w = (char*)d_ws;
    auto align = [](size_t v) { return (v + 255) & ~(size_t)255; };
    size_t off = 0;
    int* cnt = (int*)(w + off); off = align(off + (size_t)n * 4);
    int* rs  = (int*)(w + off); off = align(off + (size_t)(n + 1) * 4);
    int* cur = (int*)(w + off); off = align(off + (size_t)n * 4);
    int* nbr = (int*)(w + off); off = align(off + (size_t)E * 4);
    float* agg = (float*)(w + off); off = align(off + (size_t)n * 128 * 4);  // reused as z
    float* h   = (float*)(w + off); off = align(off + (size_t)n * 256 * 4);
    (void)ws_size; (void)n_in; (void)out_size;

    hipMemsetAsync(cnt, 0, (size_t)n * 4, stream);
    hipMemsetAsync(cur, 0, (size_t)n * 4, stream);

    count_kernel<<<2048, 256, 0, stream>>>(dstv, cnt, E);
    scan_kernel<<<1, 1024, 0, stream>>>(cnt, rs, n);
    fill_kernel<<<2048, 256, 0, stream>>>(srcv, dstv, rs, cur, nbr, E);

    // layer 1
    segmean_kernel<0><<<n, 128, 0, stream>>>(x, rs, nbr, cnt, agg);
    int mb = (n + 63) / 64;
    gemm1_kernel<<<mb, 256, 0, stream>>>(x, agg, Wr0, Wl0, bl0, h, n);

    // layer 2: aggregate z = h@Wl1 (128-dim) instead of h (256-dim)
    gemm2_kernel<<<mb, 256, 0, stream>>>(h, Wl1, Wr1, bl1, agg /*z*/, outp, n);
    segmean_kernel<1><<<n, 128, 0, stream>>>(agg, rs, nbr, cnt, outp);
}

// Round 2
// 775.562 us; speedup vs baseline: 1.3577x; 1.3577x over previous
//
#include <hip/hip_runtime.h>

typedef short bf16x8 __attribute__((ext_vector_type(8)));
typedef float f32x4 __attribute__((ext_vector_type(4)));
typedef unsigned int uint;
typedef unsigned short ushort;

__device__ inline ushort f2bf(float f) {
    uint u = __builtin_bit_cast(uint, f);
    uint r = u + 0x7fffu + ((u >> 16) & 1u);  // round-to-nearest-even
    return (ushort)(r >> 16);
}
__device__ inline float bf2f(uint lo16) {
    uint u = lo16 << 16;
    return __builtin_bit_cast(float, u);
}

// ---------------- CSR build ----------------

__global__ void count_kernel(const int* __restrict__ dst, int* __restrict__ cnt, int E) {
    for (int e = blockIdx.x * blockDim.x + threadIdx.x; e < E; e += gridDim.x * blockDim.x)
        atomicAdd(&cnt[dst[e]], 1);
}

__global__ void scan_kernel(const int* __restrict__ cnt, int* __restrict__ rs, int n) {
    __shared__ int sums[1024];
    int tid = threadIdx.x;
    int per = n / 1024 + 1;
    int base = tid * per;
    int s = 0;
    for (int i = 0; i < per; i++) {
        int idx = base + i;
        if (idx < n) s += cnt[idx];
    }
    int mine = s;
    sums[tid] = s;
    __syncthreads();
    for (int off = 1; off < 1024; off <<= 1) {
        int v = (tid >= off) ? sums[tid - off] : 0;
        __syncthreads();
        sums[tid] += v;
        __syncthreads();
    }
    int run = sums[tid] - mine;
    for (int i = 0; i < per; i++) {
        int idx = base + i;
        if (idx < n) {
            rs[idx] = run;
            run += cnt[idx];
        } else if (idx == n) {
            rs[n] = run;
        }
    }
}

__global__ void fill_kernel(const int* __restrict__ src, const int* __restrict__ dst,
                            const int* __restrict__ rs, int* __restrict__ cur,
                            int* __restrict__ nbr, int E) {
    for (int e = blockIdx.x * blockDim.x + threadIdx.x; e < E; e += gridDim.x * blockDim.x) {
        int d = dst[e];
        int p = atomicAdd(&cur[d], 1);
        nbr[rs[d] + p] = src[e];
    }
}

// ---------------- convert x (fp32) -> bf16 into A1 rows [xb(128) | aggb(128)] ----------------

__global__ void convx_kernel(const float* __restrict__ x, ushort* __restrict__ a1, int n) {
    int i = blockIdx.x * blockDim.x + threadIdx.x;  // one float4 per thread
    int total = n * 32;                             // n*128/4
    if (i >= total) return;
    int row = i >> 5, q = i & 31;
    float4 v = *(const float4*)(x + (size_t)row * 128 + q * 4);
    ushort4 o;
    o.x = f2bf(v.x); o.y = f2bf(v.y); o.z = f2bf(v.z); o.w = f2bf(v.w);
    *(ushort4*)(a1 + (size_t)row * 256 + q * 4) = o;
}

// ---------------- pack weights (fp32 [256,out]) into MFMA B-fragment order, bf16 ----------------
// packed[((cb*8+ks)*64 + l)*8 + j] = W[ks*32 + (l>>4)*8 + j][cb*16 + (l&15)]
// mode 0 (layer 1): W(k,c) = k<128 ? Wa[k*256+c]      : Wb[(k-128)*256+c]   (Wa=Wr0, Wb=Wl0)
// mode 1 (layer 2): W(k,c) = c<128 ? Wa[k*128+c]      : Wb[k*128+(c-128)]   (Wa=Wl1, Wb=Wr1)
__global__ void packw_kernel(const float* __restrict__ Wa, const float* __restrict__ Wb,
                             ushort* __restrict__ out, int mode) {
    int tile = blockIdx.x;  // 0..127 = cb*8 + ks
    int l = threadIdx.x;    // 64
    int cb = tile >> 3, ks = tile & 7;
    int col = cb * 16 + (l & 15);
    int k0 = ks * 32 + ((l >> 4) * 8);
    ushort vals[8];
#pragma unroll
    for (int j = 0; j < 8; j++) {
        int k = k0 + j;
        float f;
        if (mode == 0)
            f = (k < 128) ? Wa[(size_t)k * 256 + col] : Wb[(size_t)(k - 128) * 256 + col];
        else
            f = (col < 128) ? Wa[(size_t)k * 128 + col] : Wb[(size_t)k * 128 + (col - 128)];
        vals[j] = f2bf(f);
    }
    ushort* dst = out + ((size_t)tile * 64 + l) * 8;
#pragma unroll
    for (int j = 0; j < 8; j++) dst[j] = vals[j];
}

// ---------------- MFMA GEMM: [N,256](bf16) x [256,256](packed bf16) ----------------
// 256 threads = 4 waves; wave w computes rows [bid*64 + w*16, +16) x all 256 cols.
// LAYER 0: out_bf = relu(acc + bias)  -> hb [N,256]
// LAYER 1: cols 0..127 -> z bf16 [N,128]; cols 128..255 -> out_f fp32 [N,128] (+bias)
template <int LAYER>
__launch_bounds__(256)
__global__ void mfma_gemm_kernel(const ushort* __restrict__ A, const ushort* __restrict__ Wp,
                                 const float* __restrict__ bias, ushort* __restrict__ out_bf,
                                 float* __restrict__ out_f, int n) {
    int l = threadIdx.x & 63;
    int w = threadIdx.x >> 6;
    int row0 = blockIdx.x * 64 + w * 16;

    int arow = row0 + (l & 15);
    if (arow > n - 1) arow = n - 1;
    const ushort* ap = A + (size_t)arow * 256 + ((l >> 4) * 8);

    bf16x8 a[8];
#pragma unroll
    for (int ks = 0; ks < 8; ks++) a[ks] = *(const bf16x8*)(ap + ks * 32);

    f32x4 acc[16];
#pragma unroll
    for (int cb = 0; cb < 16; cb++) acc[cb] = (f32x4){0.f, 0.f, 0.f, 0.f};

    const bf16x8* bbase = (const bf16x8*)Wp;  // frag index = (cb*8+ks)*64 + l
#pragma unroll 2
    for (int cb = 0; cb < 16; cb++) {
        bf16x8 b[8];
#pragma unroll
        for (int ks = 0; ks < 8; ks++) b[ks] = bbase[((size_t)(cb * 8 + ks)) * 64 + l];
#pragma unroll
        for (int ks = 0; ks < 8; ks++)
            acc[cb] = __builtin_amdgcn_mfma_f32_16x16x32_bf16(a[ks], b[ks], acc[cb], 0, 0, 0);
    }

    int rbase = row0 + (l >> 4) * 4;
#pragma unroll
    for (int cb = 0; cb < 16; cb++) {
        int col = cb * 16 + (l & 15);
        if (LAYER == 0) {
            float bv = bias[col];
#pragma unroll
            for (int r = 0; r < 4; r++) {
                int row = rbase + r;
                if (row < n) {
                    float v = acc[cb][r] + bv;
                    v = v > 0.f ? v : 0.f;
                    out_bf[(size_t)row * 256 + col] = f2bf(v);
                }
            }
        } else {
            if (col < 128) {
#pragma unroll
                for (int r = 0; r < 4; r++) {
                    int row = rbase + r;
                    if (row < n) out_bf[(size_t)row * 128 + col] = f2bf(acc[cb][r]);
                }
            } else {
                float bv = bias[col - 128];
#pragma unroll
                for (int r = 0; r < 4; r++) {
                    int row = rbase + r;
                    if (row < n) out_f[(size_t)row * 128 + (col - 128)] = acc[cb][r] + bv;
                }
            }
        }
    }
}

// ---------------- segment mean over bf16 features (row = 128 bf16 = 64 uints) ----------------
// ADD=0: outb[i*128 + l] = pack(mean(2l), mean(2l+1))     (uint = 2 bf16)
// ADD=1: outf[i*128 + 2l] += mean(2l); outf[i*128+2l+1] += mean(2l+1)
template <int ADD>
__global__ void segmean_kernel(const uint* __restrict__ fp, int half, const int* __restrict__ rs,
                               const int* __restrict__ nbr, const int* __restrict__ cnt,
                               uint* __restrict__ outb, float* __restrict__ outf, int n) {
    int w = threadIdx.x >> 6;
    int l = threadIdx.x & 63;
    int i = blockIdx.x * 4 + w;
    if (i >= n) return;
    int b = rs[i], e = rs[i + 1];
    float a0 = 0.f, a1 = 0.f;
    int j = b;
    for (; j + 4 <= e; j += 4) {
        int s0 = nbr[j], s1 = nbr[j + 1], s2 = nbr[j + 2], s3 = nbr[j + 3];
        uint v0 = fp[(size_t)s0 * half + l];
        uint v1 = fp[(size_t)s1 * half + l];
        uint v2 = fp[(size_t)s2 * half + l];
        uint v3 = fp[(size_t)s3 * half + l];
        a0 += bf2f(v0 & 0xffffu) + bf2f(v1 & 0xffffu) + bf2f(v2 & 0xffffu) + bf2f(v3 & 0xffffu);
        a1 += bf2f(v0 >> 16) + bf2f(v1 >> 16) + bf2f(v2 >> 16) + bf2f(v3 >> 16);
    }
    for (; j < e; j++) {
        uint v = fp[(size_t)nbr[j] * half + l];
        a0 += bf2f(v & 0xffffu);
        a1 += bf2f(v >> 16);
    }
    int dg = cnt[i];
    float inv = 1.0f / (float)(dg > 1 ? dg : 1);
    a0 *= inv; a1 *= inv;
    if (ADD) {
        outf[(size_t)i * 128 + 2 * l] += a0;
        outf[(size_t)i * 128 + 2 * l + 1] += a1;
    } else {
        outb[(size_t)i * 128 + l] = ((uint)f2bf(a1) << 16) | (uint)f2bf(a0);
    }
}

// ---------------- launch ----------------

extern "C" void kernel_launch(void* const* d_in, const int* in_sizes, int n_in,
                              void* d_out, int out_size, void* d_ws, size_t ws_size,
                              hipStream_t stream) {
    const float* x = (const float*)d_in[0];
    const int* ei = (const int*)d_in[1];
    const float* Wl0 = (const float*)d_in[2];
    const float* bl0 = (const float*)d_in[3];
    const float* Wr0 = (const float*)d_in[4];
    const float* Wl1 = (const float*)d_in[5];
    const float* bl1 = (const float*)d_in[6];
    const float* Wr1 = (const float*)d_in[7];
    float* outp = (float*)d_out;

    int n = in_sizes[0] / 128;  // 100000
    int E = in_sizes[1] / 2;    // 1600000
    const int* srcv = ei;
    const int* dstv = ei + E;

    char* w = (char*)d_ws;
    auto align = [](size_t v) { return (v + 255) & ~(size_t)255; };
    size_t off = 0;
    int* cnt = (int*)(w + off); off = align(off + (size_t)n * 4);
    int* rs  = (int*)(w + off); off = align(off + (size_t)(n + 1) * 4);
    int* cur = (int*)(w + off); off = align(off + (size_t)n * 4);
    int* nbr = (int*)(w + off); off = align(off + (size_t)E * 4);
    ushort* a1  = (ushort*)(w + off); off = align(off + (size_t)n * 256 * 2);  // [xb | aggb]
    ushort* hb  = (ushort*)(w + off); off = align(off + (size_t)n * 256 * 2);
    ushort* zb  = (ushort*)(w + off); off = align(off + (size_t)n * 128 * 2);
    ushort* w1p = (ushort*)(w + off); off = align(off + (size_t)256 * 256 * 2);
    ushort* w2p = (ushort*)(w + off); off = align(off + (size_t)256 * 256 * 2);
    (void)ws_size; (void)n_in; (void)out_size;

    hipMemsetAsync(cnt, 0, (size_t)n * 4, stream);
    hipMemsetAsync(cur, 0, (size_t)n * 4, stream);

    // CSR + conversions/packing (independent chains)
    count_kernel<<<2048, 256, 0, stream>>>(dstv, cnt, E);
    scan_kernel<<<1, 1024, 0, stream>>>(cnt, rs, n);
    fill_kernel<<<2048, 256, 0, stream>>>(srcv, dstv, rs, cur, nbr, E);

    convx_kernel<<<(n * 32 + 255) / 256, 256, 0, stream>>>(x, a1, n);
    packw_kernel<<<128, 64, 0, stream>>>(Wr0, Wl0, w1p, 0);
    packw_kernel<<<128, 64, 0, stream>>>(Wl1, Wr1, w2p, 1);

    int segb = (n + 3) / 4;
    int mb = (n + 63) / 64;

    // layer 1: aggb = mean-gather(xb) ; hb = relu(A1 @ [Wr0;Wl0] + bl0)
    segmean_kernel<0><<<segb, 256, 0, stream>>>((const uint*)a1, 128, rs, nbr, cnt,
                                                (uint*)(a1 + 128), nullptr, n);
    mfma_gemm_kernel<0><<<mb, 256, 0, stream>>>(a1, w1p, bl0, hb, nullptr, n);

    // layer 2: z = hb@Wl1 (bf16), out = hb@Wr1 + bl1 (fp32); then out += mean-gather(z)
    mfma_gemm_kernel<1><<<mb, 256, 0, stream>>>(hb, w2p, bl1, zb, outp, n);
    segmean_kernel<1><<<segb, 256, 0, stream>>>((const uint*)zb, 64, rs, nbr, cnt,
                                                nullptr, outp, n);
}

// Round 3
// 590.645 us; speedup vs baseline: 1.7828x; 1.3131x over previous
//
#include <hip/hip_runtime.h>

typedef short bf16x8 __attribute__((ext_vector_type(8)));
typedef float f32x4 __attribute__((ext_vector_type(4)));
typedef unsigned int uint;
typedef unsigned short ushort;

__device__ inline ushort f2bf(float f) {
    uint u = __builtin_bit_cast(uint, f);
    uint r = u + 0x7fffu + ((u >> 16) & 1u);  // round-to-nearest-even
    return (ushort)(r >> 16);
}
__device__ inline float bf2f(uint lo16) {
    uint u = lo16 << 16;
    return __builtin_bit_cast(float, u);
}

// ---------------- CSR build ----------------

__global__ void count_kernel(const int* __restrict__ dst, int* __restrict__ cnt, int E) {
    for (int e = blockIdx.x * blockDim.x + threadIdx.x; e < E; e += gridDim.x * blockDim.x)
        atomicAdd(&cnt[dst[e]], 1);
}

// hierarchical scan: per-block exclusive scan + block sums
__global__ void scan1_kernel(const int* __restrict__ cnt, int* __restrict__ rs,
                             int* __restrict__ bsum, int n) {
    __shared__ int tmp[256];
    int tid = threadIdx.x;
    int idx = blockIdx.x * 256 + tid;
    int v = (idx < n) ? cnt[idx] : 0;
    tmp[tid] = v;
    __syncthreads();
#pragma unroll
    for (int off = 1; off < 256; off <<= 1) {
        int t = (tid >= off) ? tmp[tid - off] : 0;
        __syncthreads();
        tmp[tid] += t;
        __syncthreads();
    }
    if (idx < n) rs[idx] = tmp[tid] - v;  // exclusive
    if (tid == 255) bsum[blockIdx.x] = tmp[255];
}

// scan the block sums (nb <= 512) -> exclusive prefixes, in place
__global__ void scan2_kernel(int* __restrict__ bsum, int nb) {
    __shared__ int tmp[512];
    int tid = threadIdx.x;
    int v = (tid < nb) ? bsum[tid] : 0;
    tmp[tid] = v;
    __syncthreads();
#pragma unroll
    for (int off = 1; off < 512; off <<= 1) {
        int t = (tid >= off) ? tmp[tid - off] : 0;
        __syncthreads();
        tmp[tid] += t;
        __syncthreads();
    }
    if (tid < nb) bsum[tid] = tmp[tid] - v;
}

__global__ void scan3_kernel(int* __restrict__ rs, const int* __restrict__ bsum, int n, int E) {
    int idx = blockIdx.x * 256 + threadIdx.x;
    if (idx < n) rs[idx] += bsum[blockIdx.x];
    if (idx == 0) rs[n] = E;
}

__global__ void fill_kernel(const int* __restrict__ src, const int* __restrict__ dst,
                            const int* __restrict__ rs, int* __restrict__ cur,
                            int* __restrict__ nbr, int E) {
    for (int e = blockIdx.x * blockDim.x + threadIdx.x; e < E; e += gridDim.x * blockDim.x) {
        int d = dst[e];
        int p = atomicAdd(&cur[d], 1);
        nbr[rs[d] + p] = src[e];
    }
}

// ---------------- convert x (fp32) -> bf16 into A1 rows [xb(128) | aggb(128)] ----------------

__global__ void convx_kernel(const float* __restrict__ x, ushort* __restrict__ a1, int n) {
    int i = blockIdx.x * blockDim.x + threadIdx.x;  // one float4 per thread
    int total = n * 32;                             // n*128/4
    if (i >= total) return;
    int row = i >> 5, q = i & 31;
    float4 v = *(const float4*)(x + (size_t)row * 128 + q * 4);
    ushort4 o;
    o.x = f2bf(v.x); o.y = f2bf(v.y); o.z = f2bf(v.z); o.w = f2bf(v.w);
    *(ushort4*)(a1 + (size_t)row * 256 + q * 4) = o;
}

// ---------------- pack weights (fp32 [256,out]) into MFMA B-fragment order, bf16 ----------------
// packed[((cb*8+ks)*64 + l)*8 + j] = W[ks*32 + (l>>4)*8 + j][cb*16 + (l&15)]
// mode 0 (layer 1): W(k,c) = k<128 ? Wa[k*256+c]      : Wb[(k-128)*256+c]   (Wa=Wr0, Wb=Wl0)
// mode 1 (layer 2): W(k,c) = c<128 ? Wa[k*128+c]      : Wb[k*128+(c-128)]   (Wa=Wl1, Wb=Wr1)
__global__ void packw_kernel(const float* __restrict__ Wa, const float* __restrict__ Wb,
                             ushort* __restrict__ out, int mode) {
    int tile = blockIdx.x;  // 0..127 = cb*8 + ks
    int l = threadIdx.x;    // 64
    int cb = tile >> 3, ks = tile & 7;
    int col = cb * 16 + (l & 15);
    int k0 = ks * 32 + ((l >> 4) * 8);
    ushort vals[8];
#pragma unroll
    for (int j = 0; j < 8; j++) {
        int k = k0 + j;
        float f;
        if (mode == 0)
            f = (k < 128) ? Wa[(size_t)k * 256 + col] : Wb[(size_t)(k - 128) * 256 + col];
        else
            f = (col < 128) ? Wa[(size_t)k * 128 + col] : Wb[(size_t)k * 128 + (col - 128)];
        vals[j] = f2bf(f);
    }
    ushort* dst = out + ((size_t)tile * 64 + l) * 8;
#pragma unroll
    for (int j = 0; j < 8; j++) dst[j] = vals[j];
}

// ---------------- MFMA GEMM: [N,256](bf16) x [256,256](packed bf16) ----------------
// 256 threads = 4 waves; wave w computes rows [bid*64 + w*16, +16) x all 256 cols.
// LAYER 0: out_bf = relu(acc + bias)  -> hb [N,256]
// LAYER 1: cols 0..127 -> z bf16 [N,128]; cols 128..255 -> out_f fp32 [N,128] (+bias)
template <int LAYER>
__launch_bounds__(256)
__global__ void mfma_gemm_kernel(const ushort* __restrict__ A, const ushort* __restrict__ Wp,
                                 const float* __restrict__ bias, ushort* __restrict__ out_bf,
                                 float* __restrict__ out_f, int n) {
    int l = threadIdx.x & 63;
    int w = threadIdx.x >> 6;
    int row0 = blockIdx.x * 64 + w * 16;

    int arow = row0 + (l & 15);
    if (arow > n - 1) arow = n - 1;
    const ushort* ap = A + (size_t)arow * 256 + ((l >> 4) * 8);

    bf16x8 a[8];
#pragma unroll
    for (int ks = 0; ks < 8; ks++) a[ks] = *(const bf16x8*)(ap + ks * 32);

    f32x4 acc[16];
#pragma unroll
    for (int cb = 0; cb < 16; cb++) acc[cb] = (f32x4){0.f, 0.f, 0.f, 0.f};

    const bf16x8* bbase = (const bf16x8*)Wp;  // frag index = (cb*8+ks)*64 + l
#pragma unroll 2
    for (int cb = 0; cb < 16; cb++) {
        bf16x8 b[8];
#pragma unroll
        for (int ks = 0; ks < 8; ks++) b[ks] = bbase[((size_t)(cb * 8 + ks)) * 64 + l];
#pragma unroll
        for (int ks = 0; ks < 8; ks++)
            acc[cb] = __builtin_amdgcn_mfma_f32_16x16x32_bf16(a[ks], b[ks], acc[cb], 0, 0, 0);
    }

    int rbase = row0 + (l >> 4) * 4;
#pragma unroll
    for (int cb = 0; cb < 16; cb++) {
        int col = cb * 16 + (l & 15);
        if (LAYER == 0) {
            float bv = bias[col];
#pragma unroll
            for (int r = 0; r < 4; r++) {
                int row = rbase + r;
                if (row < n) {
                    float v = acc[cb][r] + bv;
                    v = v > 0.f ? v : 0.f;
                    out_bf[(size_t)row * 256 + col] = f2bf(v);
                }
            }
        } else {
            if (col < 128) {
#pragma unroll
                for (int r = 0; r < 4; r++) {
                    int row = rbase + r;
                    if (row < n) out_bf[(size_t)row * 128 + col] = f2bf(acc[cb][r]);
                }
            } else {
                float bv = bias[col - 128];
#pragma unroll
                for (int r = 0; r < 4; r++) {
                    int row = rbase + r;
                    if (row < n) out_f[(size_t)row * 128 + (col - 128)] = acc[cb][r] + bv;
                }
            }
        }
    }
}

// ---------------- segment mean over bf16 features (row = `half` uints = 2*half bf16) ----------------
// ADD=0: outb[i*half + l] = pack(mean(2l), mean(2l+1))
// ADD=1: outf[i*2*half + 2l] += mean(2l); outf[i*2*half + 2l+1] += mean(2l+1)
template <int ADD>
__global__ void segmean_kernel(const uint* __restrict__ fp, int half, const int* __restrict__ rs,
                               const int* __restrict__ nbr,
                               uint* __restrict__ outb, float* __restrict__ outf, int n) {
    int w = threadIdx.x >> 6;
    int l = threadIdx.x & 63;
    int i = blockIdx.x * 4 + w;
    if (i >= n) return;
    int b = rs[i], e = rs[i + 1];
    float a0 = 0.f, a1 = 0.f;
    int j = b;
    for (; j + 4 <= e; j += 4) {
        int s0 = nbr[j], s1 = nbr[j + 1], s2 = nbr[j + 2], s3 = nbr[j + 3];
        uint v0 = fp[(size_t)s0 * half + l];
        uint v1 = fp[(size_t)s1 * half + l];
        uint v2 = fp[(size_t)s2 * half + l];
        uint v3 = fp[(size_t)s3 * half + l];
        a0 += bf2f(v0 & 0xffffu) + bf2f(v1 & 0xffffu) + bf2f(v2 & 0xffffu) + bf2f(v3 & 0xffffu);
        a1 += bf2f(v0 >> 16) + bf2f(v1 >> 16) + bf2f(v2 >> 16) + bf2f(v3 >> 16);
    }
    for (; j < e; j++) {
        uint v = fp[(size_t)nbr[j] * half + l];
        a0 += bf2f(v & 0xffffu);
        a1 += bf2f(v >> 16);
    }
    int dg = e - b;
    float inv = 1.0f / (float)(dg > 1 ? dg : 1);
    a0 *= inv; a1 *= inv;
    if (ADD) {
        outf[(size_t)i * 2 * half + 2 * l] += a0;
        outf[(size_t)i * 2 * half + 2 * l + 1] += a1;
    } else {
        outb[(size_t)i * half + l] = ((uint)f2bf(a1) << 16) | (uint)f2bf(a0);
    }
}

// ---------------- launch ----------------

extern "C" void kernel_launch(void* const* d_in, const int* in_sizes, int n_in,
                              void* d_out, int out_size, void* d_ws, size_t ws_size,
                              hipStream_t stream) {
    const float* x = (const float*)d_in[0];
    const int* ei = (const int*)d_in[1];
    const float* Wl0 = (const float*)d_in[2];
    const float* bl0 = (const float*)d_in[3];
    const float* Wr0 = (const float*)d_in[4];
    const float* Wl1 = (const float*)d_in[5];
    const float* bl1 = (const float*)d_in[6];
    const float* Wr1 = (const float*)d_in[7];
    float* outp = (float*)d_out;

    int n = in_sizes[0] / 128;  // 100000
    int E = in_sizes[1] / 2;    // 1600000
    const int* srcv = ei;
    const int* dstv = ei + E;

    char* w = (char*)d_ws;
    auto align = [](size_t v) { return (v + 255) & ~(size_t)255; };
    size_t off = 0;
    int* cnt = (int*)(w + off); off = align(off + (size_t)n * 4);
    int* rs  = (int*)(w + off); off = align(off + (size_t)(n + 1) * 4);
    int* cur = (int*)(w + off); off = align(off + (size_t)n * 4);
    int* bsum = (int*)(w + off); off = align(off + (size_t)512 * 4);
    int* nbr = (int*)(w + off); off = align(off + (size_t)E * 4);
    ushort* a1  = (ushort*)(w + off); off = align(off + (size_t)n * 256 * 2);  // [xb | aggb]
    ushort* hb  = (ushort*)(w + off); off = align(off + (size_t)n * 256 * 2);
    ushort* zb  = (ushort*)(w + off); off = align(off + (size_t)n * 128 * 2);
    ushort* w1p = (ushort*)(w + off); off = align(off + (size_t)256 * 256 * 2);
    ushort* w2p = (ushort*)(w + off); off = align(off + (size_t)256 * 256 * 2);
    (void)ws_size; (void)n_in; (void)out_size;

    hipMemsetAsync(cnt, 0, (size_t)n * 4, stream);
    hipMemsetAsync(cur, 0, (size_t)n * 4, stream);

    int nb = (n + 255) / 256;  // 391

    // CSR build
    count_kernel<<<2048, 256, 0, stream>>>(dstv, cnt, E);
    scan1_kernel<<<nb, 256, 0, stream>>>(cnt, rs, bsum, n);
    scan2_kernel<<<1, 512, 0, stream>>>(bsum, nb);
    scan3_kernel<<<nb, 256, 0, stream>>>(rs, bsum, n, E);
    fill_kernel<<<2048, 256, 0, stream>>>(srcv, dstv, rs, cur, nbr, E);

    convx_kernel<<<(n * 32 + 255) / 256, 256, 0, stream>>>(x, a1, n);
    packw_kernel<<<128, 64, 0, stream>>>(Wr0, Wl0, w1p, 0);
    packw_kernel<<<128, 64, 0, stream>>>(Wl1, Wr1, w2p, 1);

    int segb = (n + 3) / 4;
    int mb = (n + 63) / 64;

    // layer 1: aggb = mean-gather(xb) ; hb = relu(A1 @ [Wr0;Wl0] + bl0)
    segmean_kernel<0><<<segb, 256, 0, stream>>>((const uint*)a1, 128, rs, nbr,
                                                (uint*)(a1 + 128), nullptr, n);
    mfma_gemm_kernel<0><<<mb, 256, 0, stream>>>(a1, w1p, bl0, hb, nullptr, n);

    // layer 2: z = hb@Wl1 (bf16), out = hb@Wr1 + bl1 (fp32); then out += mean-gather(z)
    mfma_gemm_kernel<1><<<mb, 256, 0, stream>>>(hb, w2p, bl1, zb, outp, n);
    segmean_kernel<1><<<segb, 256, 0, stream>>>((const uint*)zb, 64, rs, nbr,
                                                nullptr, outp, n);
}

// Round 4
// 387.078 us; speedup vs baseline: 2.7204x; 1.5259x over previous
//
#include <hip/hip_runtime.h>

typedef short bf16x8 __attribute__((ext_vector_type(8)));
typedef float f32x4 __attribute__((ext_vector_type(4)));
typedef unsigned int uint;
typedef unsigned short ushort;
typedef ushort u16x8 __attribute__((ext_vector_type(8)));
typedef uint u32x2 __attribute__((ext_vector_type(2)));
typedef uint u32x4 __attribute__((ext_vector_type(4)));

__device__ inline ushort f2bf(float f) {
    uint u = __builtin_bit_cast(uint, f);
    uint r = u + 0x7fffu + ((u >> 16) & 1u);  // round-to-nearest-even
    return (ushort)(r >> 16);
}
__device__ inline float bf2f(uint lo16) {
    uint u = lo16 << 16;
    return __builtin_bit_cast(float, u);
}

// ---------------- CSR build ----------------

__global__ void count_kernel(const int* __restrict__ dst, int* __restrict__ cnt, int E) {
    for (int e = blockIdx.x * blockDim.x + threadIdx.x; e < E; e += gridDim.x * blockDim.x)
        atomicAdd(&cnt[dst[e]], 1);
}

__global__ void scan1_kernel(const int* __restrict__ cnt, int* __restrict__ rs,
                             int* __restrict__ bsum, int n) {
    __shared__ int tmp[256];
    int tid = threadIdx.x;
    int idx = blockIdx.x * 256 + tid;
    int v = (idx < n) ? cnt[idx] : 0;
    tmp[tid] = v;
    __syncthreads();
#pragma unroll
    for (int off = 1; off < 256; off <<= 1) {
        int t = (tid >= off) ? tmp[tid - off] : 0;
        __syncthreads();
        tmp[tid] += t;
        __syncthreads();
    }
    if (idx < n) rs[idx] = tmp[tid] - v;  // exclusive
    if (tid == 255) bsum[blockIdx.x] = tmp[255];
}

__global__ void scan2_kernel(int* __restrict__ bsum, int nb) {
    __shared__ int tmp[512];
    int tid = threadIdx.x;
    int v = (tid < nb) ? bsum[tid] : 0;
    tmp[tid] = v;
    __syncthreads();
#pragma unroll
    for (int off = 1; off < 512; off <<= 1) {
        int t = (tid >= off) ? tmp[tid - off] : 0;
        __syncthreads();
        tmp[tid] += t;
        __syncthreads();
    }
    if (tid < nb) bsum[tid] = tmp[tid] - v;
}

__global__ void scan3_kernel(int* __restrict__ rs, const int* __restrict__ bsum, int n, int E) {
    int idx = blockIdx.x * 256 + threadIdx.x;
    if (idx < n) rs[idx] += bsum[blockIdx.x];
    if (idx == 0) rs[n] = E;
}

__global__ void fill_kernel(const int* __restrict__ src, const int* __restrict__ dst,
                            const int* __restrict__ rs, int* __restrict__ cur,
                            int* __restrict__ nbr, int E) {
    for (int e = blockIdx.x * blockDim.x + threadIdx.x; e < E; e += gridDim.x * blockDim.x) {
        int d = dst[e];
        int p = atomicAdd(&cur[d], 1);
        nbr[rs[d] + p] = src[e];
    }
}

// ---------------- convert x (fp32) -> bf16 into A1 rows [xb(128) | aggb(128)] ----------------

__global__ void convx_kernel(const float* __restrict__ x, ushort* __restrict__ a1, int n) {
    int i = blockIdx.x * blockDim.x + threadIdx.x;
    int total = n * 32;
    if (i >= total) return;
    int row = i >> 5, q = i & 31;
    float4 v = *(const float4*)(x + (size_t)row * 128 + q * 4);
    ushort4 o;
    o.x = f2bf(v.x); o.y = f2bf(v.y); o.z = f2bf(v.z); o.w = f2bf(v.w);
    *(ushort4*)(a1 + (size_t)row * 256 + q * 4) = o;
}

// ---------------- pack weights into MFMA B-fragment order, bf16 ----------------
// packed[((cb*8+ks)*64 + l)*8 + j] = W[ks*32 + (l>>4)*8 + j][cb*16 + (l&15)]
__global__ void packw_kernel(const float* __restrict__ Wa, const float* __restrict__ Wb,
                             ushort* __restrict__ out, int mode) {
    int tile = blockIdx.x;  // cb*8 + ks
    int l = threadIdx.x;    // 64
    int cb = tile >> 3, ks = tile & 7;
    int col = cb * 16 + (l & 15);
    int k0 = ks * 32 + ((l >> 4) * 8);
    ushort vals[8];
#pragma unroll
    for (int j = 0; j < 8; j++) {
        int k = k0 + j;
        float f;
        if (mode == 0)
            f = (k < 128) ? Wa[(size_t)k * 256 + col] : Wb[(size_t)(k - 128) * 256 + col];
        else
            f = (col < 128) ? Wa[(size_t)k * 128 + col] : Wb[(size_t)k * 128 + (col - 128)];
        vals[j] = f2bf(f);
    }
    ushort* dst = out + ((size_t)tile * 64 + l) * 8;
#pragma unroll
    for (int j = 0; j < 8; j++) dst[j] = vals[j];
}

// ---------------- MFMA GEMM v2: LDS-staged W, C^T fragments, coalesced epilogue ----------------
// 256 threads = 4 waves; block covers 128 rows; wave w: rows [bid*128 + w*32, +32) as 2 groups of 16.
// mfma(b, a, acc) yields C^T fragments: lane holds row = l&15 (+g*16), cols cb*16 + (l>>4)*4 + r.
template <int LAYER>
__launch_bounds__(256, 2)
__global__ void mfma_gemm_kernel(const ushort* __restrict__ A, const ushort* __restrict__ Wp,
                                 const float* __restrict__ bias, ushort* __restrict__ out_bf,
                                 float* __restrict__ out_f, int n) {
    __shared__ unsigned char smem[65536];
    int tid = threadIdx.x;
    int l = tid & 63, w = tid >> 6;
    int row0 = blockIdx.x * 128 + w * 32;

    // A fragments (2 row groups), loaded as 64B/row-per-instr coalesced chunks
    bf16x8 a[2][8];
#pragma unroll
    for (int g = 0; g < 2; g++) {
        int ar = row0 + g * 16 + (l & 15);
        if (ar > n - 1) ar = n - 1;
        const ushort* ap = A + (size_t)ar * 256 + ((l >> 4) * 8);
#pragma unroll
        for (int ks = 0; ks < 8; ks++) a[g][ks] = *(const bf16x8*)(ap + ks * 32);
    }

    f32x4 acc[2][16];
#pragma unroll
    for (int g = 0; g < 2; g++)
#pragma unroll
        for (int cb = 0; cb < 16; cb++) acc[g][cb] = (f32x4){0.f, 0.f, 0.f, 0.f};

    const unsigned char* wbytes = (const unsigned char*)Wp;

#pragma unroll
    for (int half = 0; half < 2; half++) {
        {  // stage 64KB half of packed W into LDS (reg-staged, coalesced 16B/lane)
            const unsigned char* src = wbytes + half * 65536;
#pragma unroll
            for (int i = 0; i < 16; i += 4) {
                u32x4 t0 = *(const u32x4*)(src + (size_t)(i + 0) * 4096 + tid * 16);
                u32x4 t1 = *(const u32x4*)(src + (size_t)(i + 1) * 4096 + tid * 16);
                u32x4 t2 = *(const u32x4*)(src + (size_t)(i + 2) * 4096 + tid * 16);
                u32x4 t3 = *(const u32x4*)(src + (size_t)(i + 3) * 4096 + tid * 16);
                *(u32x4*)(smem + (i + 0) * 4096 + tid * 16) = t0;
                *(u32x4*)(smem + (i + 1) * 4096 + tid * 16) = t1;
                *(u32x4*)(smem + (i + 2) * 4096 + tid * 16) = t2;
                *(u32x4*)(smem + (i + 3) * 4096 + tid * 16) = t3;
            }
        }
        __syncthreads();
#pragma unroll
        for (int cb = 0; cb < 8; cb++) {
            bf16x8 b[8];
            const unsigned char* bp = smem + ((size_t)(cb * 8) * 64 + l) * 16;
#pragma unroll
            for (int ks = 0; ks < 8; ks++) b[ks] = *(const bf16x8*)(bp + (size_t)ks * 1024);
#pragma unroll
            for (int ks = 0; ks < 8; ks++) {
                acc[0][half * 8 + cb] =
                    __builtin_amdgcn_mfma_f32_16x16x32_bf16(b[ks], a[0][ks], acc[0][half * 8 + cb], 0, 0, 0);
                acc[1][half * 8 + cb] =
                    __builtin_amdgcn_mfma_f32_16x16x32_bf16(b[ks], a[1][ks], acc[1][half * 8 + cb], 0, 0, 0);
            }
        }
        __syncthreads();
    }

    // ---------------- epilogue (reuses smem; per-wave private regions) ----------------
    if (LAYER == 0) {
        ushort* ep = (ushort*)(void*)smem + (size_t)w * (16 * 272);
#pragma unroll
        for (int g = 0; g < 2; g++) {
            int rbase = row0 + g * 16;
#pragma unroll
            for (int cb = 0; cb < 16; cb++) {
                int colb = cb * 16 + (l >> 4) * 4;
                f32x4 bv = *(const f32x4*)(bias + colb);
                f32x4 v = acc[g][cb];
                float v0 = fmaxf(v[0] + bv[0], 0.f);
                float v1 = fmaxf(v[1] + bv[1], 0.f);
                float v2 = fmaxf(v[2] + bv[2], 0.f);
                float v3 = fmaxf(v[3] + bv[3], 0.f);
                u32x2 pk;
                pk[0] = (uint)f2bf(v0) | ((uint)f2bf(v1) << 16);
                pk[1] = (uint)f2bf(v2) | ((uint)f2bf(v3) << 16);
                *(u32x2*)&ep[(l & 15) * 272 + colb] = pk;
            }
            int rr = l >> 2, q = l & 3;
            int row = rbase + rr;
#pragma unroll
            for (int rep = 0; rep < 8; rep++) {
                u16x8 vv = *(const u16x8*)&ep[rr * 272 + q * 8 + rep * 32];
                if (row < n)
                    *(u16x8*)(out_bf + (size_t)row * 256 + q * 8 + rep * 32) = vv;
            }
        }
    } else {
        ushort* ep = (ushort*)(void*)smem + (size_t)w * (16 * 136);
#pragma unroll
        for (int g = 0; g < 2; g++) {
            int rbase = row0 + g * 16;
            // cols 0..127 -> zb (bf16) via LDS transpose
#pragma unroll
            for (int cb = 0; cb < 8; cb++) {
                int colb = cb * 16 + (l >> 4) * 4;
                f32x4 v = acc[g][cb];
                u32x2 pk;
                pk[0] = (uint)f2bf(v[0]) | ((uint)f2bf(v[1]) << 16);
                pk[1] = (uint)f2bf(v[2]) | ((uint)f2bf(v[3]) << 16);
                *(u32x2*)&ep[(l & 15) * 136 + colb] = pk;
            }
            {
                int rr = l >> 2, q = l & 3;
                int row = rbase + rr;
#pragma unroll
                for (int rep = 0; rep < 4; rep++) {
                    u16x8 vv = *(const u16x8*)&ep[rr * 136 + q * 8 + rep * 32];
                    if (row < n)
                        *(u16x8*)(out_bf + (size_t)row * 128 + q * 8 + rep * 32) = vv;
                }
            }
            // cols 128..255 -> out fp32 (+bias), direct 16B stores (64B/row/instr)
            int orow = rbase + (l & 15);
#pragma unroll
            for (int cb = 8; cb < 16; cb++) {
                int colb = (cb - 8) * 16 + (l >> 4) * 4;
                f32x4 bv = *(const f32x4*)(bias + colb);
                f32x4 v = acc[g][cb];
                v[0] += bv[0]; v[1] += bv[1]; v[2] += bv[2]; v[3] += bv[3];
                if (orow < n)
                    *(f32x4*)(out_f + (size_t)orow * 128 + colb) = v;
            }
        }
    }
}

// ---------------- segment mean over bf16 features (row = `half` uints) ----------------
template <int ADD>
__global__ void segmean_kernel(const uint* __restrict__ fp, int half, const int* __restrict__ rs,
                               const int* __restrict__ nbr,
                               uint* __restrict__ outb, float* __restrict__ outf, int n) {
    int w = threadIdx.x >> 6;
    int l = threadIdx.x & 63;
    int i = blockIdx.x * 4 + w;
    if (i >= n) return;
    int b = rs[i], e = rs[i + 1];
    float a0 = 0.f, a1 = 0.f;
    int j = b;
    for (; j + 4 <= e; j += 4) {
        int s0 = nbr[j], s1 = nbr[j + 1], s2 = nbr[j + 2], s3 = nbr[j + 3];
        uint v0 = fp[(size_t)s0 * half + l];
        uint v1 = fp[(size_t)s1 * half + l];
        uint v2 = fp[(size_t)s2 * half + l];
        uint v3 = fp[(size_t)s3 * half + l];
        a0 += bf2f(v0 & 0xffffu) + bf2f(v1 & 0xffffu) + bf2f(v2 & 0xffffu) + bf2f(v3 & 0xffffu);
        a1 += bf2f(v0 >> 16) + bf2f(v1 >> 16) + bf2f(v2 >> 16) + bf2f(v3 >> 16);
    }
    for (; j < e; j++) {
        uint v = fp[(size_t)nbr[j] * half + l];
        a0 += bf2f(v & 0xffffu);
        a1 += bf2f(v >> 16);
    }
    int dg = e - b;
    float inv = 1.0f / (float)(dg > 1 ? dg : 1);
    a0 *= inv; a1 *= inv;
    if (ADD) {
        outf[(size_t)i * 2 * half + 2 * l] += a0;
        outf[(size_t)i * 2 * half + 2 * l + 1] += a1;
    } else {
        outb[(size_t)i * half + l] = ((uint)f2bf(a1) << 16) | (uint)f2bf(a0);
    }
}

// ---------------- launch ----------------

extern "C" void kernel_launch(void* const* d_in, const int* in_sizes, int n_in,
                              void* d_out, int out_size, void* d_ws, size_t ws_size,
                              hipStream_t stream) {
    const float* x = (const float*)d_in[0];
    const int* ei = (const int*)d_in[1];
    const float* Wl0 = (const float*)d_in[2];
    const float* bl0 = (const float*)d_in[3];
    const float* Wr0 = (const float*)d_in[4];
    const float* Wl1 = (const float*)d_in[5];
    const float* bl1 = (const float*)d_in[6];
    const float* Wr1 = (const float*)d_in[7];
    float* outp = (float*)d_out;

    int n = in_sizes[0] / 128;  // 100000
    int E = in_sizes[1] / 2;    // 1600000
    const int* srcv = ei;
    const int* dstv = ei + E;

    char* w = (char*)d_ws;
    auto align = [](size_t v) { return (v + 255) & ~(size_t)255; };
    size_t off = 0;
    int* cnt = (int*)(w + off); off = align(off + (size_t)n * 4);
    int* rs  = (int*)(w + off); off = align(off + (size_t)(n + 1) * 4);
    int* cur = (int*)(w + off); off = align(off + (size_t)n * 4);
    int* bsum = (int*)(w + off); off = align(off + (size_t)512 * 4);
    int* nbr = (int*)(w + off); off = align(off + (size_t)E * 4);
    ushort* a1  = (ushort*)(w + off); off = align(off + (size_t)n * 256 * 2);  // [xb | aggb]
    ushort* hb  = (ushort*)(w + off); off = align(off + (size_t)n * 256 * 2);
    ushort* zb  = (ushort*)(w + off); off = align(off + (size_t)n * 128 * 2);
    ushort* w1p = (ushort*)(w + off); off = align(off + (size_t)256 * 256 * 2);
    ushort* w2p = (ushort*)(w + off); off = align(off + (size_t)256 * 256 * 2);
    (void)ws_size; (void)n_in; (void)out_size;

    hipMemsetAsync(cnt, 0, (size_t)n * 4, stream);
    hipMemsetAsync(cur, 0, (size_t)n * 4, stream);

    int nb = (n + 255) / 256;

    count_kernel<<<2048, 256, 0, stream>>>(dstv, cnt, E);
    scan1_kernel<<<nb, 256, 0, stream>>>(cnt, rs, bsum, n);
    scan2_kernel<<<1, 512, 0, stream>>>(bsum, nb);
    scan3_kernel<<<nb, 256, 0, stream>>>(rs, bsum, n, E);
    fill_kernel<<<2048, 256, 0, stream>>>(srcv, dstv, rs, cur, nbr, E);

    convx_kernel<<<(n * 32 + 255) / 256, 256, 0, stream>>>(x, a1, n);
    packw_kernel<<<128, 64, 0, stream>>>(Wr0, Wl0, w1p, 0);
    packw_kernel<<<128, 64, 0, stream>>>(Wl1, Wr1, w2p, 1);

    int segb = (n + 3) / 4;
    int mb = (n + 127) / 128;

    // layer 1: aggb = mean-gather(xb) ; hb = relu(A1 @ [Wr0;Wl0] + bl0)
    segmean_kernel<0><<<segb, 256, 0, stream>>>((const uint*)a1, 128, rs, nbr,
                                                (uint*)(a1 + 128), nullptr, n);
    mfma_gemm_kernel<0><<<mb, 256, 0, stream>>>(a1, w1p, bl0, hb, nullptr, n);

    // layer 2: z = hb@Wl1 (bf16), out = hb@Wr1 + bl1 (fp32); then out += mean-gather(z)
    mfma_gemm_kernel<1><<<mb, 256, 0, stream>>>(hb, w2p, bl1, zb, outp, n);
    segmean_kernel<1><<<segb, 256, 0, stream>>>((const uint*)zb, 64, rs, nbr,
                                                nullptr, outp, n);
}

// Round 5
// 342.543 us; speedup vs baseline: 3.0740x; 1.1300x over previous
//
#include <hip/hip_runtime.h>

typedef short bf16x8 __attribute__((ext_vector_type(8)));
typedef float f32x4 __attribute__((ext_vector_type(4)));
typedef unsigned int uint;
typedef unsigned short ushort;
typedef ushort u16x8 __attribute__((ext_vector_type(8)));
typedef uint u32x2 __attribute__((ext_vector_type(2)));
typedef uint u32x4 __attribute__((ext_vector_type(4)));

#define NBLK 256  // edge-chunk blocks for P1/P3

__device__ inline ushort f2bf(float f) {
    uint u = __builtin_bit_cast(uint, f);
    uint r = u + 0x7fffu + ((u >> 16) & 1u);  // round-to-nearest-even
    return (ushort)(r >> 16);
}
__device__ inline float bf2f(uint lo16) {
    uint u = lo16 << 16;
    return __builtin_bit_cast(float, u);
}

// ---------------- CSR build, bucketed ----------------
// P1: per-node counts (global atomics) + per-(bucket,block) histogram
__global__ void p1_kernel(const int* __restrict__ dst, int* __restrict__ cnt,
                          int* __restrict__ ghist, int E, int CE, int NB) {
    __shared__ int hist[512];
    int tid = threadIdx.x;
    for (int b = tid; b < NB; b += 256) hist[b] = 0;
    __syncthreads();
    int start = blockIdx.x * CE, end = min(E, start + CE);
    for (int e = start + tid; e < end; e += 256) {
        int d = dst[e];
        atomicAdd(&cnt[d], 1);
        atomicAdd(&hist[d >> 8], 1);
    }
    __syncthreads();
    for (int b = tid; b < NB; b += 256) ghist[(size_t)b * NBLK + blockIdx.x] = hist[b];
}

// hierarchical exclusive scan (generic): scan1 + scan2 + scan3
__global__ void scan1_kernel(const int* __restrict__ cnt, int* __restrict__ rs,
                             int* __restrict__ bsum, int n) {
    __shared__ int tmp[256];
    int tid = threadIdx.x;
    int idx = blockIdx.x * 256 + tid;
    int v = (idx < n) ? cnt[idx] : 0;
    tmp[tid] = v;
    __syncthreads();
#pragma unroll
    for (int off = 1; off < 256; off <<= 1) {
        int t = (tid >= off) ? tmp[tid - off] : 0;
        __syncthreads();
        tmp[tid] += t;
        __syncthreads();
    }
    if (idx < n) rs[idx] = tmp[tid] - v;  // exclusive
    if (tid == 255) bsum[blockIdx.x] = tmp[255];
}

__global__ void scan2_kernel(int* __restrict__ bsum, int nb) {
    __shared__ int tmp[512];
    int tid = threadIdx.x;
    int v = (tid < nb) ? bsum[tid] : 0;
    tmp[tid] = v;
    __syncthreads();
#pragma unroll
    for (int off = 1; off < 512; off <<= 1) {
        int t = (tid >= off) ? tmp[tid - off] : 0;
        __syncthreads();
        tmp[tid] += t;
        __syncthreads();
    }
    if (tid < nb) bsum[tid] = tmp[tid] - v;
}

__global__ void scan3_kernel(int* __restrict__ rs, const int* __restrict__ bsum, int n, int E) {
    int idx = blockIdx.x * 256 + threadIdx.x;
    if (idx < n) rs[idx] += bsum[blockIdx.x];
    if (idx == 0) rs[n] = E;
}

// P3: partition edges into bucket-major ebuck; payload = (dstLocal<<17)|src (src<2^17)
__global__ void p3_kernel(const int* __restrict__ src, const int* __restrict__ dst,
                          const int* __restrict__ goff, uint* __restrict__ ebuck,
                          int E, int CE, int NB) {
    __shared__ int cur[512];
    int tid = threadIdx.x;
    for (int b = tid; b < NB; b += 256) cur[b] = goff[(size_t)b * NBLK + blockIdx.x];
    __syncthreads();
    int start = blockIdx.x * CE, end = min(E, start + CE);
    for (int e = start + tid; e < end; e += 256) {
        int d = dst[e];
        int s = src[e];
        int slot = atomicAdd(&cur[d >> 8], 1);
        ebuck[slot] = ((uint)(d & 255) << 17) | (uint)s;
    }
}

// P4: one block per bucket; LDS per-node cursors seeded from rs; local scatter into nbr
__global__ void p4_kernel(const uint* __restrict__ ebuck, const int* __restrict__ rs,
                          int* __restrict__ nbr, int n) {
    __shared__ int cur[257];
    int tid = threadIdx.x;
    int d0 = blockIdx.x << 8;
    int d1 = min(n, d0 + 256);
    int nn = d1 - d0;
    for (int i = tid; i < nn; i += 256) cur[i] = rs[d0 + i];
    __syncthreads();
    int eb = rs[d0], ee = rs[d1];
    for (int e = eb + tid; e < ee; e += 256) {
        uint v = ebuck[e];
        int dl = v >> 17;
        int s = (int)(v & 0x1FFFFu);
        int p = atomicAdd(&cur[dl], 1);
        nbr[p] = s;
    }
}

// ---------------- convert x (fp32) -> bf16 into A1 rows [xb(128) | aggb(128)] ----------------

__global__ void convx_kernel(const float* __restrict__ x, ushort* __restrict__ a1, int n) {
    int i = blockIdx.x * blockDim.x + threadIdx.x;
    int total = n * 32;
    if (i >= total) return;
    int row = i >> 5, q = i & 31;
    float4 v = *(const float4*)(x + (size_t)row * 128 + q * 4);
    ushort4 o;
    o.x = f2bf(v.x); o.y = f2bf(v.y); o.z = f2bf(v.z); o.w = f2bf(v.w);
    *(ushort4*)(a1 + (size_t)row * 256 + q * 4) = o;
}

// ---------------- pack weights into MFMA B-fragment order, bf16 ----------------
__global__ void packw_kernel(const float* __restrict__ Wa, const float* __restrict__ Wb,
                             ushort* __restrict__ out, int mode) {
    int tile = blockIdx.x;  // cb*8 + ks
    int l = threadIdx.x;    // 64
    int cb = tile >> 3, ks = tile & 7;
    int col = cb * 16 + (l & 15);
    int k0 = ks * 32 + ((l >> 4) * 8);
    ushort vals[8];
#pragma unroll
    for (int j = 0; j < 8; j++) {
        int k = k0 + j;
        float f;
        if (mode == 0)
            f = (k < 128) ? Wa[(size_t)k * 256 + col] : Wb[(size_t)(k - 128) * 256 + col];
        else
            f = (col < 128) ? Wa[(size_t)k * 128 + col] : Wb[(size_t)k * 128 + (col - 128)];
        vals[j] = f2bf(f);
    }
    ushort* dst = out + ((size_t)tile * 64 + l) * 8;
#pragma unroll
    for (int j = 0; j < 8; j++) dst[j] = vals[j];
}

// ---------------- MFMA GEMM: LDS-staged W, C^T fragments, coalesced epilogue ----------------
template <int LAYER>
__launch_bounds__(256, 2)
__global__ void mfma_gemm_kernel(const ushort* __restrict__ A, const ushort* __restrict__ Wp,
                                 const float* __restrict__ bias, ushort* __restrict__ out_bf,
                                 float* __restrict__ out_f, int n) {
    __shared__ unsigned char smem[65536];
    int tid = threadIdx.x;
    int l = tid & 63, w = tid >> 6;
    int row0 = blockIdx.x * 128 + w * 32;

    bf16x8 a[2][8];
#pragma unroll
    for (int g = 0; g < 2; g++) {
        int ar = row0 + g * 16 + (l & 15);
        if (ar > n - 1) ar = n - 1;
        const ushort* ap = A + (size_t)ar * 256 + ((l >> 4) * 8);
#pragma unroll
        for (int ks = 0; ks < 8; ks++) a[g][ks] = *(const bf16x8*)(ap + ks * 32);
    }

    f32x4 acc[2][16];
#pragma unroll
    for (int g = 0; g < 2; g++)
#pragma unroll
        for (int cb = 0; cb < 16; cb++) acc[g][cb] = (f32x4){0.f, 0.f, 0.f, 0.f};

    const unsigned char* wbytes = (const unsigned char*)Wp;

#pragma unroll
    for (int half = 0; half < 2; half++) {
        {
            const unsigned char* src = wbytes + half * 65536;
#pragma unroll
            for (int i = 0; i < 16; i += 4) {
                u32x4 t0 = *(const u32x4*)(src + (size_t)(i + 0) * 4096 + tid * 16);
                u32x4 t1 = *(const u32x4*)(src + (size_t)(i + 1) * 4096 + tid * 16);
                u32x4 t2 = *(const u32x4*)(src + (size_t)(i + 2) * 4096 + tid * 16);
                u32x4 t3 = *(const u32x4*)(src + (size_t)(i + 3) * 4096 + tid * 16);
                *(u32x4*)(smem + (i + 0) * 4096 + tid * 16) = t0;
                *(u32x4*)(smem + (i + 1) * 4096 + tid * 16) = t1;
                *(u32x4*)(smem + (i + 2) * 4096 + tid * 16) = t2;
                *(u32x4*)(smem + (i + 3) * 4096 + tid * 16) = t3;
            }
        }
        __syncthreads();
#pragma unroll
        for (int cb = 0; cb < 8; cb++) {
            bf16x8 b[8];
            const unsigned char* bp = smem + ((size_t)(cb * 8) * 64 + l) * 16;
#pragma unroll
            for (int ks = 0; ks < 8; ks++) b[ks] = *(const bf16x8*)(bp + (size_t)ks * 1024);
#pragma unroll
            for (int ks = 0; ks < 8; ks++) {
                acc[0][half * 8 + cb] =
                    __builtin_amdgcn_mfma_f32_16x16x32_bf16(b[ks], a[0][ks], acc[0][half * 8 + cb], 0, 0, 0);
                acc[1][half * 8 + cb] =
                    __builtin_amdgcn_mfma_f32_16x16x32_bf16(b[ks], a[1][ks], acc[1][half * 8 + cb], 0, 0, 0);
            }
        }
        __syncthreads();
    }

    if (LAYER == 0) {
        ushort* ep = (ushort*)(void*)smem + (size_t)w * (16 * 272);
#pragma unroll
        for (int g = 0; g < 2; g++) {
            int rbase = row0 + g * 16;
#pragma unroll
            for (int cb = 0; cb < 16; cb++) {
                int colb = cb * 16 + (l >> 4) * 4;
                f32x4 bv = *(const f32x4*)(bias + colb);
                f32x4 v = acc[g][cb];
                float v0 = fmaxf(v[0] + bv[0], 0.f);
                float v1 = fmaxf(v[1] + bv[1], 0.f);
                float v2 = fmaxf(v[2] + bv[2], 0.f);
                float v3 = fmaxf(v[3] + bv[3], 0.f);
                u32x2 pk;
                pk[0] = (uint)f2bf(v0) | ((uint)f2bf(v1) << 16);
                pk[1] = (uint)f2bf(v2) | ((uint)f2bf(v3) << 16);
                *(u32x2*)&ep[(l & 15) * 272 + colb] = pk;
            }
            int rr = l >> 2, q = l & 3;
            int row = rbase + rr;
#pragma unroll
            for (int rep = 0; rep < 8; rep++) {
                u16x8 vv = *(const u16x8*)&ep[rr * 272 + q * 8 + rep * 32];
                if (row < n)
                    *(u16x8*)(out_bf + (size_t)row * 256 + q * 8 + rep * 32) = vv;
            }
        }
    } else {
        ushort* ep = (ushort*)(void*)smem + (size_t)w * (16 * 136);
#pragma unroll
        for (int g = 0; g < 2; g++) {
            int rbase = row0 + g * 16;
#pragma unroll
            for (int cb = 0; cb < 8; cb++) {
                int colb = cb * 16 + (l >> 4) * 4;
                f32x4 v = acc[g][cb];
                u32x2 pk;
                pk[0] = (uint)f2bf(v[0]) | ((uint)f2bf(v[1]) << 16);
                pk[1] = (uint)f2bf(v[2]) | ((uint)f2bf(v[3]) << 16);
                *(u32x2*)&ep[(l & 15) * 136 + colb] = pk;
            }
            {
                int rr = l >> 2, q = l & 3;
                int row = rbase + rr;
#pragma unroll
                for (int rep = 0; rep < 4; rep++) {
                    u16x8 vv = *(const u16x8*)&ep[rr * 136 + q * 8 + rep * 32];
                    if (row < n)
                        *(u16x8*)(out_bf + (size_t)row * 128 + q * 8 + rep * 32) = vv;
                }
            }
            int orow = rbase + (l & 15);
#pragma unroll
            for (int cb = 8; cb < 16; cb++) {
                int colb = (cb - 8) * 16 + (l >> 4) * 4;
                f32x4 bv = *(const f32x4*)(bias + colb);
                f32x4 v = acc[g][cb];
                v[0] += bv[0]; v[1] += bv[1]; v[2] += bv[2]; v[3] += bv[3];
                if (orow < n)
                    *(f32x4*)(out_f + (size_t)orow * 128 + colb) = v;
            }
        }
    }
}

// ---------------- segment mean over bf16 features (row = `half` uints) ----------------
template <int ADD>
__global__ void segmean_kernel(const uint* __restrict__ fp, int half, const int* __restrict__ rs,
                               const int* __restrict__ nbr,
                               uint* __restrict__ outb, float* __restrict__ outf, int n) {
    int w = threadIdx.x >> 6;
    int l = threadIdx.x & 63;
    int i = blockIdx.x * 4 + w;
    if (i >= n) return;
    int b = rs[i], e = rs[i + 1];
    float a0 = 0.f, a1 = 0.f;
    int j = b;
    for (; j + 4 <= e; j += 4) {
        int s0 = nbr[j], s1 = nbr[j + 1], s2 = nbr[j + 2], s3 = nbr[j + 3];
        uint v0 = fp[(size_t)s0 * half + l];
        uint v1 = fp[(size_t)s1 * half + l];
        uint v2 = fp[(size_t)s2 * half + l];
        uint v3 = fp[(size_t)s3 * half + l];
        a0 += bf2f(v0 & 0xffffu) + bf2f(v1 & 0xffffu) + bf2f(v2 & 0xffffu) + bf2f(v3 & 0xffffu);
        a1 += bf2f(v0 >> 16) + bf2f(v1 >> 16) + bf2f(v2 >> 16) + bf2f(v3 >> 16);
    }
    for (; j < e; j++) {
        uint v = fp[(size_t)nbr[j] * half + l];
        a0 += bf2f(v & 0xffffu);
        a1 += bf2f(v >> 16);
    }
    int dg = e - b;
    float inv = 1.0f / (float)(dg > 1 ? dg : 1);
    a0 *= inv; a1 *= inv;
    if (ADD) {
        outf[(size_t)i * 2 * half + 2 * l] += a0;
        outf[(size_t)i * 2 * half + 2 * l + 1] += a1;
    } else {
        outb[(size_t)i * half + l] = ((uint)f2bf(a1) << 16) | (uint)f2bf(a0);
    }
}

// ---------------- launch ----------------

extern "C" void kernel_launch(void* const* d_in, const int* in_sizes, int n_in,
                              void* d_out, int out_size, void* d_ws, size_t ws_size,
                              hipStream_t stream) {
    const float* x = (const float*)d_in[0];
    const int* ei = (const int*)d_in[1];
    const float* Wl0 = (const float*)d_in[2];
    const float* bl0 = (const float*)d_in[3];
    const float* Wr0 = (const float*)d_in[4];
    const float* Wl1 = (const float*)d_in[5];
    const float* bl1 = (const float*)d_in[6];
    const float* Wr1 = (const float*)d_in[7];
    float* outp = (float*)d_out;

    int n = in_sizes[0] / 128;  // 100000
    int E = in_sizes[1] / 2;    // 1600000
    const int* srcv = ei;
    const int* dstv = ei + E;

    int NB = (n + 255) >> 8;        // 391 dst buckets
    int NG = NB * NBLK;             // ghist entries
    int CE = (E + NBLK - 1) / NBLK; // edges per P1/P3 block

    char* w = (char*)d_ws;
    auto align = [](size_t v) { return (v + 255) & ~(size_t)255; };
    size_t off = 0;
    int* cnt   = (int*)(w + off); off = align(off + (size_t)n * 4);
    int* rs    = (int*)(w + off); off = align(off + (size_t)(n + 1) * 4);
    int* bsum  = (int*)(w + off); off = align(off + (size_t)512 * 4);
    int* bsum2 = (int*)(w + off); off = align(off + (size_t)512 * 4);
    int* ghist = (int*)(w + off); off = align(off + (size_t)(NG + 1) * 4);
    int* goff  = (int*)(w + off); off = align(off + (size_t)(NG + 1) * 4);
    uint* ebuck = (uint*)(w + off); off = align(off + (size_t)E * 4);
    int* nbr   = (int*)(w + off); off = align(off + (size_t)E * 4);
    ushort* a1  = (ushort*)(w + off); off = align(off + (size_t)n * 256 * 2);  // [xb | aggb]
    ushort* hb  = (ushort*)(w + off); off = align(off + (size_t)n * 256 * 2);
    ushort* zb  = (ushort*)(w + off); off = align(off + (size_t)n * 128 * 2);
    ushort* w1p = (ushort*)(w + off); off = align(off + (size_t)256 * 256 * 2);
    ushort* w2p = (ushort*)(w + off); off = align(off + (size_t)256 * 256 * 2);
    (void)ws_size; (void)n_in; (void)out_size;

    hipMemsetAsync(cnt, 0, (size_t)n * 4, stream);

    int nb = (n + 255) / 256;    // 391
    int nb2 = (NG + 255) / 256;  // 392

    // CSR build (bucketed)
    p1_kernel<<<NBLK, 256, 0, stream>>>(dstv, cnt, ghist, E, CE, NB);
    scan1_kernel<<<nb, 256, 0, stream>>>(cnt, rs, bsum, n);
    scan2_kernel<<<1, 512, 0, stream>>>(bsum, nb);
    scan3_kernel<<<nb, 256, 0, stream>>>(rs, bsum, n, E);
    scan1_kernel<<<nb2, 256, 0, stream>>>(ghist, goff, bsum2, NG);
    scan2_kernel<<<1, 512, 0, stream>>>(bsum2, nb2);
    scan3_kernel<<<nb2, 256, 0, stream>>>(goff, bsum2, NG, E);
    p3_kernel<<<NBLK, 256, 0, stream>>>(srcv, dstv, goff, ebuck, E, CE, NB);
    p4_kernel<<<NB, 256, 0, stream>>>(ebuck, rs, nbr, n);

    convx_kernel<<<(n * 32 + 255) / 256, 256, 0, stream>>>(x, a1, n);
    packw_kernel<<<128, 64, 0, stream>>>(Wr0, Wl0, w1p, 0);
    packw_kernel<<<128, 64, 0, stream>>>(Wl1, Wr1, w2p, 1);

    int segb = (n + 3) / 4;
    int mb = (n + 127) / 128;

    // layer 1: aggb = mean-gather(xb) ; hb = relu(A1 @ [Wr0;Wl0] + bl0)
    segmean_kernel<0><<<segb, 256, 0, stream>>>((const uint*)a1, 128, rs, nbr,
                                                (uint*)(a1 + 128), nullptr, n);
    mfma_gemm_kernel<0><<<mb, 256, 0, stream>>>(a1, w1p, bl0, hb, nullptr, n);

    // layer 2: z = hb@Wl1 (bf16), out = hb@Wr1 + bl1 (fp32); then out += mean-gather(z)
    mfma_gemm_kernel<1><<<mb, 256, 0, stream>>>(hb, w2p, bl1, zb, outp, n);
    segmean_kernel<1><<<segb, 256, 0, stream>>>((const uint*)zb, 64, rs, nbr,
                                                nullptr, outp, n);
}

// Round 6
// 273.153 us; speedup vs baseline: 3.8549x; 1.2540x over previous
//
#include <hip/hip_runtime.h>

typedef short bf16x8 __attribute__((ext_vector_type(8)));
typedef float f32x4 __attribute__((ext_vector_type(4)));
typedef unsigned int uint;
typedef unsigned short ushort;
typedef ushort u16x8 __attribute__((ext_vector_type(8)));
typedef uint u32x2 __attribute__((ext_vector_type(2)));
typedef uint u32x4 __attribute__((ext_vector_type(4)));

#define NBLK 256   // edge-chunk blocks for P1/P3
#define LCAP 24576 // p4 LDS edge buffer (96 KB); avg bucket ~4.1K edges

__device__ inline ushort f2bf(float f) {
    uint u = __builtin_bit_cast(uint, f);
    uint r = u + 0x7fffu + ((u >> 16) & 1u);  // round-to-nearest-even
    return (ushort)(r >> 16);
}
__device__ inline float bf2f(uint lo16) {
    uint u = lo16 << 16;
    return __builtin_bit_cast(float, u);
}

// ---------------- CSR build, bucketed (no per-node global atomics) ----------------
// P1: per-(bucket,block) histogram only
__global__ void p1_kernel(const int* __restrict__ dst, int* __restrict__ ghist,
                          int E, int CE, int NB) {
    __shared__ int hist[512];
    int tid = threadIdx.x;
    for (int b = tid; b < NB; b += 256) hist[b] = 0;
    __syncthreads();
    int start = blockIdx.x * CE, end = min(E, start + CE);
    for (int e = start + tid; e < end; e += 256) {
        int d = dst[e];
        atomicAdd(&hist[d >> 8], 1);
    }
    __syncthreads();
    for (int b = tid; b < NB; b += 256) ghist[(size_t)b * NBLK + blockIdx.x] = hist[b];
}

// hierarchical exclusive scan over ghist (NG entries)
__global__ void scan1_kernel(const int* __restrict__ cnt, int* __restrict__ rs,
                             int* __restrict__ bsum, int n) {
    __shared__ int tmp[256];
    int tid = threadIdx.x;
    int idx = blockIdx.x * 256 + tid;
    int v = (idx < n) ? cnt[idx] : 0;
    tmp[tid] = v;
    __syncthreads();
#pragma unroll
    for (int off = 1; off < 256; off <<= 1) {
        int t = (tid >= off) ? tmp[tid - off] : 0;
        __syncthreads();
        tmp[tid] += t;
        __syncthreads();
    }
    if (idx < n) rs[idx] = tmp[tid] - v;  // exclusive
    if (tid == 255) bsum[blockIdx.x] = tmp[255];
}

__global__ void scan2_kernel(int* __restrict__ bsum, int nb) {
    __shared__ int tmp[512];
    int tid = threadIdx.x;
    int v = (tid < nb) ? bsum[tid] : 0;
    tmp[tid] = v;
    __syncthreads();
#pragma unroll
    for (int off = 1; off < 512; off <<= 1) {
        int t = (tid >= off) ? tmp[tid - off] : 0;
        __syncthreads();
        tmp[tid] += t;
        __syncthreads();
    }
    if (tid < nb) bsum[tid] = tmp[tid] - v;
}

__global__ void scan3_kernel(int* __restrict__ rs, const int* __restrict__ bsum, int n, int E) {
    int idx = blockIdx.x * 256 + threadIdx.x;
    if (idx < n) rs[idx] += bsum[blockIdx.x];
    if (idx == 0) rs[n] = E;
}

// P3: partition edges into bucket-major ebuck; payload = (dstLocal<<17)|src (src<2^17)
__global__ void p3_kernel(const int* __restrict__ src, const int* __restrict__ dst,
                          const int* __restrict__ goff, uint* __restrict__ ebuck,
                          int E, int CE, int NB) {
    __shared__ int cur[512];
    int tid = threadIdx.x;
    for (int b = tid; b < NB; b += 256) cur[b] = goff[(size_t)b * NBLK + blockIdx.x];
    __syncthreads();
    int start = blockIdx.x * CE, end = min(E, start + CE);
    for (int e = start + tid; e < end; e += 256) {
        int d = dst[e];
        int s = src[e];
        int slot = atomicAdd(&cur[d >> 8], 1);
        ebuck[slot] = ((uint)(d & 255) << 17) | (uint)s;
    }
}

// P4: one block per bucket. LDS-stage edge slice, histogram per-node counts,
// block-scan -> write rs slice, then scatter src into nbr.
__global__ void p4_kernel(const uint* __restrict__ ebuck, const int* __restrict__ goff,
                          int* __restrict__ rs, int* __restrict__ nbr, int n, int E, int NB) {
    __shared__ uint ebuf[LCAP];
    __shared__ int cnt[256];
    __shared__ int cur[256];
    int tid = threadIdx.x;
    int b = blockIdx.x;
    int d0 = b << 8;
    int eb = goff[(size_t)b * NBLK];
    int ee = (b == NB - 1) ? E : goff[(size_t)(b + 1) * NBLK];
    cnt[tid] = 0;
    __syncthreads();
    int m = ee - eb;
    for (int i = tid; i < m; i += 256) {
        uint v = ebuck[eb + i];
        if (i < LCAP) ebuf[i] = v;
        atomicAdd(&cnt[v >> 17], 1);
    }
    __syncthreads();
    // exclusive scan of cnt (Hillis-Steele via cur as temp)
    int v0 = cnt[tid];
    cur[tid] = v0;
    __syncthreads();
#pragma unroll
    for (int off = 1; off < 256; off <<= 1) {
        int t = (tid >= off) ? cur[tid - off] : 0;
        __syncthreads();
        cur[tid] += t;
        __syncthreads();
    }
    int excl = cur[tid] - v0;
    int node = d0 + tid;
    if (node < n) rs[node] = eb + excl;
    if (b == NB - 1 && tid == 0) rs[n] = E;
    __syncthreads();
    cur[tid] = eb + excl;
    __syncthreads();
    for (int i = tid; i < m; i += 256) {
        uint v = (i < LCAP) ? ebuf[i] : ebuck[eb + i];
        int p = atomicAdd(&cur[v >> 17], 1);
        nbr[p] = (int)(v & 0x1FFFFu);
    }
}

// ---------------- convert x (fp32) -> bf16 into A1 rows [xb(128) | aggb(128)] ----------------

__global__ void convx_kernel(const float* __restrict__ x, ushort* __restrict__ a1, int n) {
    int i = blockIdx.x * blockDim.x + threadIdx.x;
    int total = n * 32;
    if (i >= total) return;
    int row = i >> 5, q = i & 31;
    float4 v = *(const float4*)(x + (size_t)row * 128 + q * 4);
    ushort4 o;
    o.x = f2bf(v.x); o.y = f2bf(v.y); o.z = f2bf(v.z); o.w = f2bf(v.w);
    *(ushort4*)(a1 + (size_t)row * 256 + q * 4) = o;
}

// ---------------- pack weights into MFMA B-fragment order, bf16 ----------------
__global__ void packw_kernel(const float* __restrict__ Wa, const float* __restrict__ Wb,
                             ushort* __restrict__ out, int mode) {
    int tile = blockIdx.x;  // cb*8 + ks
    int l = threadIdx.x;    // 64
    int cb = tile >> 3, ks = tile & 7;
    int col = cb * 16 + (l & 15);
    int k0 = ks * 32 + ((l >> 4) * 8);
    ushort vals[8];
#pragma unroll
    for (int j = 0; j < 8; j++) {
        int k = k0 + j;
        float f;
        if (mode == 0)
            f = (k < 128) ? Wa[(size_t)k * 256 + col] : Wb[(size_t)(k - 128) * 256 + col];
        else
            f = (col < 128) ? Wa[(size_t)k * 128 + col] : Wb[(size_t)k * 128 + (col - 128)];
        vals[j] = f2bf(f);
    }
    ushort* dst = out + ((size_t)tile * 64 + l) * 8;
#pragma unroll
    for (int j = 0; j < 8; j++) dst[j] = vals[j];
}

// ---------------- MFMA GEMM: LDS-staged W, C^T fragments, coalesced epilogue ----------------
template <int LAYER>
__launch_bounds__(256, 2)
__global__ void mfma_gemm_kernel(const ushort* __restrict__ A, const ushort* __restrict__ Wp,
                                 const float* __restrict__ bias, ushort* __restrict__ out_bf,
                                 float* __restrict__ out_f, int n) {
    __shared__ unsigned char smem[65536];
    int tid = threadIdx.x;
    int l = tid & 63, w = tid >> 6;
    int row0 = blockIdx.x * 128 + w * 32;

    bf16x8 a[2][8];
#pragma unroll
    for (int g = 0; g < 2; g++) {
        int ar = row0 + g * 16 + (l & 15);
        if (ar > n - 1) ar = n - 1;
        const ushort* ap = A + (size_t)ar * 256 + ((l >> 4) * 8);
#pragma unroll
        for (int ks = 0; ks < 8; ks++) a[g][ks] = *(const bf16x8*)(ap + ks * 32);
    }

    f32x4 acc[2][16];
#pragma unroll
    for (int g = 0; g < 2; g++)
#pragma unroll
        for (int cb = 0; cb < 16; cb++) acc[g][cb] = (f32x4){0.f, 0.f, 0.f, 0.f};

    const unsigned char* wbytes = (const unsigned char*)Wp;

#pragma unroll
    for (int half = 0; half < 2; half++) {
        {
            const unsigned char* src = wbytes + half * 65536;
#pragma unroll
            for (int i = 0; i < 16; i += 4) {
                u32x4 t0 = *(const u32x4*)(src + (size_t)(i + 0) * 4096 + tid * 16);
                u32x4 t1 = *(const u32x4*)(src + (size_t)(i + 1) * 4096 + tid * 16);
                u32x4 t2 = *(const u32x4*)(src + (size_t)(i + 2) * 4096 + tid * 16);
                u32x4 t3 = *(const u32x4*)(src + (size_t)(i + 3) * 4096 + tid * 16);
                *(u32x4*)(smem + (i + 0) * 4096 + tid * 16) = t0;
                *(u32x4*)(smem + (i + 1) * 4096 + tid * 16) = t1;
                *(u32x4*)(smem + (i + 2) * 4096 + tid * 16) = t2;
                *(u32x4*)(smem + (i + 3) * 4096 + tid * 16) = t3;
            }
        }
        __syncthreads();
#pragma unroll
        for (int cb = 0; cb < 8; cb++) {
            bf16x8 b[8];
            const unsigned char* bp = smem + ((size_t)(cb * 8) * 64 + l) * 16;
#pragma unroll
            for (int ks = 0; ks < 8; ks++) b[ks] = *(const bf16x8*)(bp + (size_t)ks * 1024);
#pragma unroll
            for (int ks = 0; ks < 8; ks++) {
                acc[0][half * 8 + cb] =
                    __builtin_amdgcn_mfma_f32_16x16x32_bf16(b[ks], a[0][ks], acc[0][half * 8 + cb], 0, 0, 0);
                acc[1][half * 8 + cb] =
                    __builtin_amdgcn_mfma_f32_16x16x32_bf16(b[ks], a[1][ks], acc[1][half * 8 + cb], 0, 0, 0);
            }
        }
        __syncthreads();
    }

    if (LAYER == 0) {
        ushort* ep = (ushort*)(void*)smem + (size_t)w * (16 * 272);
#pragma unroll
        for (int g = 0; g < 2; g++) {
            int rbase = row0 + g * 16;
#pragma unroll
            for (int cb = 0; cb < 16; cb++) {
                int colb = cb * 16 + (l >> 4) * 4;
                f32x4 bv = *(const f32x4*)(bias + colb);
                f32x4 v = acc[g][cb];
                float v0 = fmaxf(v[0] + bv[0], 0.f);
                float v1 = fmaxf(v[1] + bv[1], 0.f);
                float v2 = fmaxf(v[2] + bv[2], 0.f);
                float v3 = fmaxf(v[3] + bv[3], 0.f);
                u32x2 pk;
                pk[0] = (uint)f2bf(v0) | ((uint)f2bf(v1) << 16);
                pk[1] = (uint)f2bf(v2) | ((uint)f2bf(v3) << 16);
                *(u32x2*)&ep[(l & 15) * 272 + colb] = pk;
            }
            int rr = l >> 2, q = l & 3;
            int row = rbase + rr;
#pragma unroll
            for (int rep = 0; rep < 8; rep++) {
                u16x8 vv = *(const u16x8*)&ep[rr * 272 + q * 8 + rep * 32];
                if (row < n)
                    *(u16x8*)(out_bf + (size_t)row * 256 + q * 8 + rep * 32) = vv;
            }
        }
    } else {
        ushort* ep = (ushort*)(void*)smem + (size_t)w * (16 * 136);
#pragma unroll
        for (int g = 0; g < 2; g++) {
            int rbase = row0 + g * 16;
#pragma unroll
            for (int cb = 0; cb < 8; cb++) {
                int colb = cb * 16 + (l >> 4) * 4;
                f32x4 v = acc[g][cb];
                u32x2 pk;
                pk[0] = (uint)f2bf(v[0]) | ((uint)f2bf(v[1]) << 16);
                pk[1] = (uint)f2bf(v[2]) | ((uint)f2bf(v[3]) << 16);
                *(u32x2*)&ep[(l & 15) * 136 + colb] = pk;
            }
            {
                int rr = l >> 2, q = l & 3;
                int row = rbase + rr;
#pragma unroll
                for (int rep = 0; rep < 4; rep++) {
                    u16x8 vv = *(const u16x8*)&ep[rr * 136 + q * 8 + rep * 32];
                    if (row < n)
                        *(u16x8*)(out_bf + (size_t)row * 128 + q * 8 + rep * 32) = vv;
                }
            }
            int orow = rbase + (l & 15);
#pragma unroll
            for (int cb = 8; cb < 16; cb++) {
                int colb = (cb - 8) * 16 + (l >> 4) * 4;
                f32x4 bv = *(const f32x4*)(bias + colb);
                f32x4 v = acc[g][cb];
                v[0] += bv[0]; v[1] += bv[1]; v[2] += bv[2]; v[3] += bv[3];
                if (orow < n)
                    *(f32x4*)(out_f + (size_t)orow * 128 + colb) = v;
            }
        }
    }
}

// ---------------- segment mean over bf16 features (row = `half` uints) ----------------
template <int ADD>
__global__ void segmean_kernel(const uint* __restrict__ fp, int half, const int* __restrict__ rs,
                               const int* __restrict__ nbr,
                               uint* __restrict__ outb, float* __restrict__ outf, int n) {
    int w = threadIdx.x >> 6;
    int l = threadIdx.x & 63;
    int i = blockIdx.x * 4 + w;
    if (i >= n) return;
    int b = rs[i], e = rs[i + 1];
    const uint* fpl = fp + l;
    float a0 = 0.f, a1 = 0.f;
    int j = b;
    for (; j + 8 <= e; j += 8) {
        int s[8];
#pragma unroll
        for (int q = 0; q < 8; q++) s[q] = nbr[j + q];
        uint v[8];
#pragma unroll
        for (int q = 0; q < 8; q++) v[q] = fpl[(size_t)s[q] * half];
#pragma unroll
        for (int q = 0; q < 8; q++) {
            a0 += bf2f(v[q] & 0xffffu);
            a1 += bf2f(v[q] >> 16);
        }
    }
    for (; j + 2 <= e; j += 2) {
        int s0 = nbr[j], s1 = nbr[j + 1];
        uint v0 = fpl[(size_t)s0 * half];
        uint v1 = fpl[(size_t)s1 * half];
        a0 += bf2f(v0 & 0xffffu) + bf2f(v1 & 0xffffu);
        a1 += bf2f(v0 >> 16) + bf2f(v1 >> 16);
    }
    for (; j < e; j++) {
        uint v = fpl[(size_t)nbr[j] * half];
        a0 += bf2f(v & 0xffffu);
        a1 += bf2f(v >> 16);
    }
    int dg = e - b;
    float inv = 1.0f / (float)(dg > 1 ? dg : 1);
    a0 *= inv; a1 *= inv;
    if (ADD) {
        outf[(size_t)i * 2 * half + 2 * l] += a0;
        outf[(size_t)i * 2 * half + 2 * l + 1] += a1;
    } else {
        outb[(size_t)i * half + l] = ((uint)f2bf(a1) << 16) | (uint)f2bf(a0);
    }
}

// ---------------- launch ----------------

extern "C" void kernel_launch(void* const* d_in, const int* in_sizes, int n_in,
                              void* d_out, int out_size, void* d_ws, size_t ws_size,
                              hipStream_t stream) {
    const float* x = (const float*)d_in[0];
    const int* ei = (const int*)d_in[1];
    const float* Wl0 = (const float*)d_in[2];
    const float* bl0 = (const float*)d_in[3];
    const float* Wr0 = (const float*)d_in[4];
    const float* Wl1 = (const float*)d_in[5];
    const float* bl1 = (const float*)d_in[6];
    const float* Wr1 = (const float*)d_in[7];
    float* outp = (float*)d_out;

    int n = in_sizes[0] / 128;  // 100000
    int E = in_sizes[1] / 2;    // 1600000
    const int* srcv = ei;
    const int* dstv = ei + E;

    int NB = (n + 255) >> 8;        // 391 dst buckets
    int NG = NB * NBLK;             // ghist entries
    int CE = (E + NBLK - 1) / NBLK; // edges per P1/P3 block

    char* w = (char*)d_ws;
    auto align = [](size_t v) { return (v + 255) & ~(size_t)255; };
    size_t off = 0;
    int* rs    = (int*)(w + off); off = align(off + (size_t)(n + 1) * 4);
    int* bsum2 = (int*)(w + off); off = align(off + (size_t)512 * 4);
    int* ghist = (int*)(w + off); off = align(off + (size_t)(NG + 1) * 4);
    int* goff  = (int*)(w + off); off = align(off + (size_t)(NG + 1) * 4);
    uint* ebuck = (uint*)(w + off); off = align(off + (size_t)E * 4);
    int* nbr   = (int*)(w + off); off = align(off + (size_t)E * 4);
    ushort* a1  = (ushort*)(w + off); off = align(off + (size_t)n * 256 * 2);  // [xb | aggb]
    ushort* hb  = (ushort*)(w + off); off = align(off + (size_t)n * 256 * 2);
    ushort* zb  = (ushort*)(w + off); off = align(off + (size_t)n * 128 * 2);
    ushort* w1p = (ushort*)(w + off); off = align(off + (size_t)256 * 256 * 2);
    ushort* w2p = (ushort*)(w + off); off = align(off + (size_t)256 * 256 * 2);
    (void)ws_size; (void)n_in; (void)out_size;

    int nb2 = (NG + 255) / 256;  // 392

    // CSR build (bucketed, no global count atomics)
    p1_kernel<<<NBLK, 256, 0, stream>>>(dstv, ghist, E, CE, NB);
    scan1_kernel<<<nb2, 256, 0, stream>>>(ghist, goff, bsum2, NG);
    scan2_kernel<<<1, 512, 0, stream>>>(bsum2, nb2);
    scan3_kernel<<<nb2, 256, 0, stream>>>(goff, bsum2, NG, E);
    p3_kernel<<<NBLK, 256, 0, stream>>>(srcv, dstv, goff, ebuck, E, CE, NB);
    p4_kernel<<<NB, 256, 0, stream>>>(ebuck, goff, rs, nbr, n, E, NB);

    convx_kernel<<<(n * 32 + 255) / 256, 256, 0, stream>>>(x, a1, n);
    packw_kernel<<<128, 64, 0, stream>>>(Wr0, Wl0, w1p, 0);
    packw_kernel<<<128, 64, 0, stream>>>(Wl1, Wr1, w2p, 1);

    int segb = (n + 3) / 4;
    int mb = (n + 127) / 128;

    // layer 1: aggb = mean-gather(xb) ; hb = relu(A1 @ [Wr0;Wl0] + bl0)
    segmean_kernel<0><<<segb, 256, 0, stream>>>((const uint*)a1, 128, rs, nbr,
                                                (uint*)(a1 + 128), nullptr, n);
    mfma_gemm_kernel<0><<<mb, 256, 0, stream>>>(a1, w1p, bl0, hb, nullptr, n);

    // layer 2: z = hb@Wl1 (bf16), out = hb@Wr1 + bl1 (fp32); then out += mean-gather(z)
    mfma_gemm_kernel<1><<<mb, 256, 0, stream>>>(hb, w2p, bl1, zb, outp, n);
    segmean_kernel<1><<<segb, 256, 0, stream>>>((const uint*)zb, 64, rs, nbr,
                                                nullptr, outp, n);
}

// Round 7
// 266.582 us; speedup vs baseline: 3.9499x; 1.0246x over previous
//
#include <hip/hip_runtime.h>

typedef short bf16x8 __attribute__((ext_vector_type(8)));
typedef float f32x4 __attribute__((ext_vector_type(4)));
typedef unsigned int uint;
typedef unsigned short ushort;
typedef ushort u16x8 __attribute__((ext_vector_type(8)));
typedef uint u32x2 __attribute__((ext_vector_type(2)));
typedef uint u32x4 __attribute__((ext_vector_type(4)));

#define NBLK 256   // edge-chunk blocks for P1/P3
#define LCAP 24576 // p4 LDS edge buffer (96 KB)

__device__ inline ushort f2bf(float f) {
    uint u = __builtin_bit_cast(uint, f);
    uint r = u + 0x7fffu + ((u >> 16) & 1u);  // round-to-nearest-even
    return (ushort)(r >> 16);
}
__device__ inline float bf2f(uint lo16) {
    uint u = lo16 << 16;
    return __builtin_bit_cast(float, u);
}
__device__ inline float bf2f_hi(uint v) {  // high bf16 of a uint: single v_and
    uint u = v & 0xffff0000u;
    return __builtin_bit_cast(float, u);
}

// ---------------- packw helper: fp32 W -> MFMA B-fragment order, bf16 ----------------
// packed[((cb*8+ks)*64 + l)*8 + j] = W[ks*32 + (l>>4)*8 + j][cb*16 + (l&15)]
__device__ inline void packw_body(const float* __restrict__ Wa, const float* __restrict__ Wb,
                                  ushort* __restrict__ out, int mode, int tile, int l) {
    int cb = tile >> 3, ks = tile & 7;
    int col = cb * 16 + (l & 15);
    int k0 = ks * 32 + ((l >> 4) * 8);
    ushort vals[8];
#pragma unroll
    for (int j = 0; j < 8; j++) {
        int k = k0 + j;
        float f;
        if (mode == 0)
            f = (k < 128) ? Wa[(size_t)k * 256 + col] : Wb[(size_t)(k - 128) * 256 + col];
        else
            f = (col < 128) ? Wa[(size_t)k * 128 + col] : Wb[(size_t)k * 128 + (col - 128)];
        vals[j] = f2bf(f);
    }
    ushort* dst = out + ((size_t)tile * 64 + l) * 8;
#pragma unroll
    for (int j = 0; j < 8; j++) dst[j] = vals[j];
}

// ---------------- fused prep: p1 histogram + packw x2 + convx ----------------
__global__ void prep_kernel(const float* __restrict__ x, ushort* __restrict__ a1,
                            const float* __restrict__ Wr0, const float* __restrict__ Wl0,
                            ushort* __restrict__ w1p,
                            const float* __restrict__ Wl1, const float* __restrict__ Wr1,
                            ushort* __restrict__ w2p,
                            const int* __restrict__ dst, int* __restrict__ ghist,
                            int E, int CE, int NB, int n) {
    __shared__ int hist[512];
    int bb = blockIdx.x;
    int tid = threadIdx.x;
    if (bb < NBLK) {
        // p1: per-(bucket,block) histogram
        for (int b = tid; b < NB; b += 256) hist[b] = 0;
        __syncthreads();
        int start = bb * CE, end = min(E, start + CE);
        for (int e = start + tid; e < end; e += 256) {
            int d = dst[e];
            atomicAdd(&hist[d >> 8], 1);
        }
        __syncthreads();
        for (int b = tid; b < NB; b += 256) ghist[(size_t)b * NBLK + bb] = hist[b];
    } else if (bb < NBLK + 64) {
        int r = bb - NBLK;
        int tile = (r & 31) * 4 + (tid >> 6);
        int l = tid & 63;
        if (r < 32) packw_body(Wr0, Wl0, w1p, 0, tile, l);
        else        packw_body(Wl1, Wr1, w2p, 1, tile, l);
    } else {
        int i = (bb - NBLK - 64) * 256 + tid;  // one float4 per thread
        int total = n * 32;
        if (i < total) {
            int row = i >> 5, q = i & 31;
            float4 v = *(const float4*)(x + (size_t)row * 128 + q * 4);
            ushort4 o;
            o.x = f2bf(v.x); o.y = f2bf(v.y); o.z = f2bf(v.z); o.w = f2bf(v.w);
            *(ushort4*)(a1 + (size_t)row * 256 + q * 4) = o;
        }
    }
}

// ---------------- hierarchical scan: scan1 (per-block) + scan23 (offset add) ----------------
__global__ void scan1_kernel(const int* __restrict__ cnt, int* __restrict__ rs,
                             int* __restrict__ bsum, int n) {
    __shared__ int tmp[256];
    int tid = threadIdx.x;
    int idx = blockIdx.x * 256 + tid;
    int v = (idx < n) ? cnt[idx] : 0;
    tmp[tid] = v;
    __syncthreads();
#pragma unroll
    for (int off = 1; off < 256; off <<= 1) {
        int t = (tid >= off) ? tmp[tid - off] : 0;
        __syncthreads();
        tmp[tid] += t;
        __syncthreads();
    }
    if (idx < n) rs[idx] = tmp[tid] - v;  // exclusive
    if (tid == 255) bsum[blockIdx.x] = tmp[255];
}

// each block computes its own prefix of bsum (<=512 entries) then adds
__global__ void scan23_kernel(int* __restrict__ rs, const int* __restrict__ bsum,
                              int n, int E) {
    __shared__ int red[256];
    int tid = threadIdx.x;
    int b = blockIdx.x;
    int s = 0;
    for (int t = tid; t < b; t += 256) s += bsum[t];
    red[tid] = s;
    __syncthreads();
#pragma unroll
    for (int off = 128; off > 0; off >>= 1) {
        if (tid < off) red[tid] += red[tid + off];
        __syncthreads();
    }
    int offv = red[0];
    int idx = b * 256 + tid;
    if (idx < n) rs[idx] += offv;
    if (b == 0 && tid == 0) rs[n] = E;
}

// P3: partition edges into bucket-major ebuck; payload = (dstLocal<<17)|src (src<2^17)
__global__ void p3_kernel(const int* __restrict__ src, const int* __restrict__ dst,
                          const int* __restrict__ goff, uint* __restrict__ ebuck,
                          int E, int CE, int NB) {
    __shared__ int cur[512];
    int tid = threadIdx.x;
    for (int b = tid; b < NB; b += 256) cur[b] = goff[(size_t)b * NBLK + blockIdx.x];
    __syncthreads();
    int start = blockIdx.x * CE, end = min(E, start + CE);
    for (int e = start + tid; e < end; e += 256) {
        int d = dst[e];
        int s = src[e];
        int slot = atomicAdd(&cur[d >> 8], 1);
        ebuck[slot] = ((uint)(d & 255) << 17) | (uint)s;
    }
}

// P4: one block per bucket; LDS-stage slice, per-node counts, block scan -> rs, scatter nbr
__global__ void p4_kernel(const uint* __restrict__ ebuck, const int* __restrict__ goff,
                          int* __restrict__ rs, int* __restrict__ nbr, int n, int E, int NB) {
    __shared__ uint ebuf[LCAP];
    __shared__ int cnt[256];
    __shared__ int cur[256];
    int tid = threadIdx.x;
    int b = blockIdx.x;
    int d0 = b << 8;
    int eb = goff[(size_t)b * NBLK];
    int ee = (b == NB - 1) ? E : goff[(size_t)(b + 1) * NBLK];
    cnt[tid] = 0;
    __syncthreads();
    int m = ee - eb;
    for (int i = tid; i < m; i += 256) {
        uint v = ebuck[eb + i];
        if (i < LCAP) ebuf[i] = v;
        atomicAdd(&cnt[v >> 17], 1);
    }
    __syncthreads();
    int v0 = cnt[tid];
    cur[tid] = v0;
    __syncthreads();
#pragma unroll
    for (int off = 1; off < 256; off <<= 1) {
        int t = (tid >= off) ? cur[tid - off] : 0;
        __syncthreads();
        cur[tid] += t;
        __syncthreads();
    }
    int excl = cur[tid] - v0;
    int node = d0 + tid;
    if (node < n) rs[node] = eb + excl;
    if (b == NB - 1 && tid == 0) rs[n] = E;
    __syncthreads();
    cur[tid] = eb + excl;
    __syncthreads();
    for (int i = tid; i < m; i += 256) {
        uint v = (i < LCAP) ? ebuf[i] : ebuck[eb + i];
        int p = atomicAdd(&cur[v >> 17], 1);
        nbr[p] = (int)(v & 0x1FFFFu);
    }
}

// ---------------- MFMA GEMM: LDS-staged W, C^T fragments, coalesced epilogue ----------------
template <int LAYER>
__launch_bounds__(256, 2)
__global__ void mfma_gemm_kernel(const ushort* __restrict__ A, const ushort* __restrict__ Wp,
                                 const float* __restrict__ bias, ushort* __restrict__ out_bf,
                                 float* __restrict__ out_f, int n) {
    __shared__ unsigned char smem[65536];
    int tid = threadIdx.x;
    int l = tid & 63, w = tid >> 6;
    int row0 = blockIdx.x * 128 + w * 32;

    bf16x8 a[2][8];
#pragma unroll
    for (int g = 0; g < 2; g++) {
        int ar = row0 + g * 16 + (l & 15);
        if (ar > n - 1) ar = n - 1;
        const ushort* ap = A + (size_t)ar * 256 + ((l >> 4) * 8);
#pragma unroll
        for (int ks = 0; ks < 8; ks++) a[g][ks] = *(const bf16x8*)(ap + ks * 32);
    }

    f32x4 acc[2][16];
#pragma unroll
    for (int g = 0; g < 2; g++)
#pragma unroll
        for (int cb = 0; cb < 16; cb++) acc[g][cb] = (f32x4){0.f, 0.f, 0.f, 0.f};

    const unsigned char* wbytes = (const unsigned char*)Wp;

#pragma unroll
    for (int half = 0; half < 2; half++) {
        {
            const unsigned char* src = wbytes + half * 65536;
#pragma unroll
            for (int i = 0; i < 16; i += 4) {
                u32x4 t0 = *(const u32x4*)(src + (size_t)(i + 0) * 4096 + tid * 16);
                u32x4 t1 = *(const u32x4*)(src + (size_t)(i + 1) * 4096 + tid * 16);
                u32x4 t2 = *(const u32x4*)(src + (size_t)(i + 2) * 4096 + tid * 16);
                u32x4 t3 = *(const u32x4*)(src + (size_t)(i + 3) * 4096 + tid * 16);
                *(u32x4*)(smem + (i + 0) * 4096 + tid * 16) = t0;
                *(u32x4*)(smem + (i + 1) * 4096 + tid * 16) = t1;
                *(u32x4*)(smem + (i + 2) * 4096 + tid * 16) = t2;
                *(u32x4*)(smem + (i + 3) * 4096 + tid * 16) = t3;
            }
        }
        __syncthreads();
#pragma unroll
        for (int cb = 0; cb < 8; cb++) {
            bf16x8 b[8];
            const unsigned char* bp = smem + ((size_t)(cb * 8) * 64 + l) * 16;
#pragma unroll
            for (int ks = 0; ks < 8; ks++) b[ks] = *(const bf16x8*)(bp + (size_t)ks * 1024);
#pragma unroll
            for (int ks = 0; ks < 8; ks++) {
                acc[0][half * 8 + cb] =
                    __builtin_amdgcn_mfma_f32_16x16x32_bf16(b[ks], a[0][ks], acc[0][half * 8 + cb], 0, 0, 0);
                acc[1][half * 8 + cb] =
                    __builtin_amdgcn_mfma_f32_16x16x32_bf16(b[ks], a[1][ks], acc[1][half * 8 + cb], 0, 0, 0);
            }
        }
        __syncthreads();
    }

    if (LAYER == 0) {
        ushort* ep = (ushort*)(void*)smem + (size_t)w * (16 * 272);
#pragma unroll
        for (int g = 0; g < 2; g++) {
            int rbase = row0 + g * 16;
#pragma unroll
            for (int cb = 0; cb < 16; cb++) {
                int colb = cb * 16 + (l >> 4) * 4;
                f32x4 bv = *(const f32x4*)(bias + colb);
                f32x4 v = acc[g][cb];
                float v0 = fmaxf(v[0] + bv[0], 0.f);
                float v1 = fmaxf(v[1] + bv[1], 0.f);
                float v2 = fmaxf(v[2] + bv[2], 0.f);
                float v3 = fmaxf(v[3] + bv[3], 0.f);
                u32x2 pk;
                pk[0] = (uint)f2bf(v0) | ((uint)f2bf(v1) << 16);
                pk[1] = (uint)f2bf(v2) | ((uint)f2bf(v3) << 16);
                *(u32x2*)&ep[(l & 15) * 272 + colb] = pk;
            }
            int rr = l >> 2, q = l & 3;
            int row = rbase + rr;
#pragma unroll
            for (int rep = 0; rep < 8; rep++) {
                u16x8 vv = *(const u16x8*)&ep[rr * 272 + q * 8 + rep * 32];
                if (row < n)
                    *(u16x8*)(out_bf + (size_t)row * 256 + q * 8 + rep * 32) = vv;
            }
        }
    } else {
        ushort* ep = (ushort*)(void*)smem + (size_t)w * (16 * 136);
#pragma unroll
        for (int g = 0; g < 2; g++) {
            int rbase = row0 + g * 16;
#pragma unroll
            for (int cb = 0; cb < 8; cb++) {
                int colb = cb * 16 + (l >> 4) * 4;
                f32x4 v = acc[g][cb];
                u32x2 pk;
                pk[0] = (uint)f2bf(v[0]) | ((uint)f2bf(v[1]) << 16);
                pk[1] = (uint)f2bf(v[2]) | ((uint)f2bf(v[3]) << 16);
                *(u32x2*)&ep[(l & 15) * 136 + colb] = pk;
            }
            {
                int rr = l >> 2, q = l & 3;
                int row = rbase + rr;
#pragma unroll
                for (int rep = 0; rep < 4; rep++) {
                    u16x8 vv = *(const u16x8*)&ep[rr * 136 + q * 8 + rep * 32];
                    if (row < n)
                        *(u16x8*)(out_bf + (size_t)row * 128 + q * 8 + rep * 32) = vv;
                }
            }
            int orow = rbase + (l & 15);
#pragma unroll
            for (int cb = 8; cb < 16; cb++) {
                int colb = (cb - 8) * 16 + (l >> 4) * 4;
                f32x4 bv = *(const f32x4*)(bias + colb);
                f32x4 v = acc[g][cb];
                v[0] += bv[0]; v[1] += bv[1]; v[2] += bv[2]; v[3] += bv[3];
                if (orow < n)
                    *(f32x4*)(out_f + (size_t)orow * 128 + colb) = v;
            }
        }
    }
}

// ---------------- segment mean v2: 2 rows per load instruction ----------------
// wave handles one dst node; lanes 0-31 = even edges, 32-63 = odd edges;
// lane q=l&31 covers features 4q..4q+3 (one uint2 / 8B per row).
template <int ADD>
__global__ void segmean_kernel(const uint* __restrict__ fp, int half /*uints per row*/,
                               const int* __restrict__ rs, const int* __restrict__ nbr,
                               uint* __restrict__ outb, float* __restrict__ outf, int n) {
    int w = threadIdx.x >> 6;
    int l = threadIdx.x & 63;
    int i = blockIdx.x * 4 + w;
    if (i >= n) return;
    int b = rs[i], e = rs[i + 1];
    int q = l & 31;
    int hsel = l >> 5;
    int stride2 = half >> 1;  // uint2 per row
    const uint2* fpq = (const uint2*)fp + q;
    float a0 = 0.f, a1 = 0.f, a2 = 0.f, a3 = 0.f;
    int j = b;
    for (; j + 8 <= e; j += 8) {
        int s[4];
#pragma unroll
        for (int p = 0; p < 4; p++) s[p] = nbr[j + 2 * p + hsel];
        uint2 v[4];
#pragma unroll
        for (int p = 0; p < 4; p++) v[p] = fpq[(size_t)s[p] * stride2];
#pragma unroll
        for (int p = 0; p < 4; p++) {
            a0 += bf2f(v[p].x & 0xffffu); a1 += bf2f_hi(v[p].x);
            a2 += bf2f(v[p].y & 0xffffu); a3 += bf2f_hi(v[p].y);
        }
    }
    for (; j + 2 <= e; j += 2) {
        int s = nbr[j + hsel];
        uint2 v = fpq[(size_t)s * stride2];
        a0 += bf2f(v.x & 0xffffu); a1 += bf2f_hi(v.x);
        a2 += bf2f(v.y & 0xffffu); a3 += bf2f_hi(v.y);
    }
    if (j < e && hsel == 0) {  // odd leftover handled by low half only
        int s = nbr[j];
        uint2 v = fpq[(size_t)s * stride2];
        a0 += bf2f(v.x & 0xffffu); a1 += bf2f_hi(v.x);
        a2 += bf2f(v.y & 0xffffu); a3 += bf2f_hi(v.y);
    }
    a0 += __shfl_xor(a0, 32);
    a1 += __shfl_xor(a1, 32);
    a2 += __shfl_xor(a2, 32);
    a3 += __shfl_xor(a3, 32);
    if (hsel == 0) {
        int dg = e - b;
        float inv = 1.0f / (float)(dg > 1 ? dg : 1);
        a0 *= inv; a1 *= inv; a2 *= inv; a3 *= inv;
        if (ADD) {
            float* op = outf + (size_t)i * (2 * half) + q * 4;
            f32x4 o = *(const f32x4*)op;
            o[0] += a0; o[1] += a1; o[2] += a2; o[3] += a3;
            *(f32x4*)op = o;
        } else {
            u32x2 pk;
            pk[0] = (uint)f2bf(a0) | ((uint)f2bf(a1) << 16);
            pk[1] = (uint)f2bf(a2) | ((uint)f2bf(a3) << 16);
            *(u32x2*)(outb + (size_t)i * half + q * 2) = pk;
        }
    }
}

// ---------------- launch ----------------

extern "C" void kernel_launch(void* const* d_in, const int* in_sizes, int n_in,
                              void* d_out, int out_size, void* d_ws, size_t ws_size,
                              hipStream_t stream) {
    const float* x = (const float*)d_in[0];
    const int* ei = (const int*)d_in[1];
    const float* Wl0 = (const float*)d_in[2];
    const float* bl0 = (const float*)d_in[3];
    const float* Wr0 = (const float*)d_in[4];
    const float* Wl1 = (const float*)d_in[5];
    const float* bl1 = (const float*)d_in[6];
    const float* Wr1 = (const float*)d_in[7];
    float* outp = (float*)d_out;

    int n = in_sizes[0] / 128;  // 100000
    int E = in_sizes[1] / 2;    // 1600000
    const int* srcv = ei;
    const int* dstv = ei + E;

    int NB = (n + 255) >> 8;        // 391 dst buckets
    int NG = NB * NBLK;             // ghist entries
    int CE = (E + NBLK - 1) / NBLK; // edges per P1/P3 block

    char* w = (char*)d_ws;
    auto align = [](size_t v) { return (v + 255) & ~(size_t)255; };
    size_t off = 0;
    int* rs    = (int*)(w + off); off = align(off + (size_t)(n + 1) * 4);
    int* bsum2 = (int*)(w + off); off = align(off + (size_t)512 * 4);
    int* ghist = (int*)(w + off); off = align(off + (size_t)(NG + 1) * 4);
    int* goff  = (int*)(w + off); off = align(off + (size_t)(NG + 1) * 4);
    uint* ebuck = (uint*)(w + off); off = align(off + (size_t)E * 4);
    int* nbr   = (int*)(w + off); off = align(off + (size_t)E * 4);
    ushort* a1  = (ushort*)(w + off); off = align(off + (size_t)n * 256 * 2);  // [xb | aggb]
    ushort* hb  = (ushort*)(w + off); off = align(off + (size_t)n * 256 * 2);
    ushort* zb  = (ushort*)(w + off); off = align(off + (size_t)n * 128 * 2);
    ushort* w1p = (ushort*)(w + off); off = align(off + (size_t)256 * 256 * 2);
    ushort* w2p = (ushort*)(w + off); off = align(off + (size_t)256 * 256 * 2);
    (void)ws_size; (void)n_in; (void)out_size;

    int nb2 = (NG + 255) / 256;       // 392
    int ncx = (n * 32 + 255) / 256;   // 12500

    // fused prep: p1 histogram + packw x2 + convx
    prep_kernel<<<NBLK + 64 + ncx, 256, 0, stream>>>(x, a1, Wr0, Wl0, w1p, Wl1, Wr1, w2p,
                                                     dstv, ghist, E, CE, NB, n);
    scan1_kernel<<<nb2, 256, 0, stream>>>(ghist, goff, bsum2, NG);
    scan23_kernel<<<nb2, 256, 0, stream>>>(goff, bsum2, NG, E);
    p3_kernel<<<NBLK, 256, 0, stream>>>(srcv, dstv, goff, ebuck, E, CE, NB);
    p4_kernel<<<NB, 256, 0, stream>>>(ebuck, goff, rs, nbr, n, E, NB);

    int segb = (n + 3) / 4;
    int mb = (n + 127) / 128;

    // layer 1: aggb = mean-gather(xb) ; hb = relu(A1 @ [Wr0;Wl0] + bl0)
    segmean_kernel<0><<<segb, 256, 0, stream>>>((const uint*)a1, 128, rs, nbr,
                                                (uint*)(a1 + 128), nullptr, n);
    mfma_gemm_kernel<0><<<mb, 256, 0, stream>>>(a1, w1p, bl0, hb, nullptr, n);

    // layer 2: z = hb@Wl1 (bf16), out = hb@Wr1 + bl1 (fp32); then out += mean-gather(z)
    mfma_gemm_kernel<1><<<mb, 256, 0, stream>>>(hb, w2p, bl1, zb, outp, n);
    segmean_kernel<1><<<segb, 256, 0, stream>>>((const uint*)zb, 64, rs, nbr,
                                                nullptr, outp, n);
}